// Round 2
// baseline (764.999 us; speedup 1.0000x reference)
//
#include <hip/hip_runtime.h>
#include <math.h>

#define NTOK 4096   // B*T tokens
#define DIM  1024
#define HID  4096
#define NEXP 8
#define NROW 8192   // NTOK * K (top-2): every token occupies exactly 2 rows
#define KSPLIT 4    // split-K factor for gemm2 (parallelism: 512 -> 2048 blocks)

typedef __bf16 bf16;
typedef __attribute__((ext_vector_type(8))) __bf16 bf16x8;
typedef __attribute__((ext_vector_type(4))) float floatx4;

// async global->LDS, 16B per lane. LDS dest is wave-uniform base + lane*16.
__device__ __forceinline__ void gl_lds16(const bf16* g, bf16* l) {
    __builtin_amdgcn_global_load_lds(
        (const __attribute__((address_space(1))) void*)g,
        (__attribute__((address_space(3))) void*)l, 16, 0, 0);
}

__global__ void zero_k(int* __restrict__ p) {
    if (threadIdx.x < 16) p[threadIdx.x] = 0;   // counts[8] + counts2[8]
}

// zero ybuf (fp32 accumulator for split-K atomics): 32 MiB
__global__ __launch_bounds__(256) void zeroy_k(float* __restrict__ p) {
    size_t i = ((size_t)blockIdx.x * 256 + threadIdx.x) * 4;
    *(floatx4*)(p + i) = floatx4{0.f, 0.f, 0.f, 0.f};
}

// ---- convert x (fp32) -> bf16 xb for the MFMA path
__global__ __launch_bounds__(256) void convx_k(const float* __restrict__ x,
                                               bf16* __restrict__ xb)
{
    size_t gid = (size_t)blockIdx.x * 256 + threadIdx.x;
    size_t eo = gid * 8;
    floatx4 a = *(const floatx4*)(x + eo);
    floatx4 b = *(const floatx4*)(x + eo + 4);
    bf16x8 v;
#pragma unroll
    for (int j = 0; j < 4; ++j) { v[j] = (bf16)a[j]; v[4 + j] = (bf16)b[j]; }
    *(bf16x8*)&xb[eo] = v;
}

// ---------------- router: one wave per token, FULL FP32 (top-k must match np ref exactly) ----
__global__ __launch_bounds__(256) void router_k(
    const float* __restrict__ x, const float* __restrict__ gw, const float* __restrict__ gb,
    int* __restrict__ counts, int* __restrict__ tok_e, float* __restrict__ tok_g)
{
    __shared__ __align__(16) float gws[DIM * NEXP];   // 32 KB fp32
    int t = threadIdx.x;
#pragma unroll
    for (int i = 0; i < 8; ++i)
        *(floatx4*)&gws[(t * 8 + i) * 4] = *(const floatx4*)&gw[(t * 8 + i) * 4];
    __syncthreads();

    int gid = blockIdx.x * 256 + t;
    int wv = gid >> 6, lane = gid & 63;       // grid covers exactly NTOK waves
    const float* xr = x + (size_t)wv * DIM;
    float acc[NEXP];
#pragma unroll
    for (int e = 0; e < NEXP; ++e) acc[e] = 0.f;
    int d0 = lane * 16;
#pragma unroll
    for (int j = 0; j < 16; ++j) {
        float xv = xr[d0 + j];
#pragma unroll
        for (int e = 0; e < NEXP; ++e) acc[e] += xv * gws[(d0 + j) * NEXP + e];
    }
#pragma unroll
    for (int off = 32; off > 0; off >>= 1) {
#pragma unroll
        for (int e = 0; e < NEXP; ++e) acc[e] += __shfl_xor(acc[e], off, 64);
    }
    if (lane == 0) {
        float lg[NEXP], m = -1e30f;
        for (int e = 0; e < NEXP; ++e) { lg[e] = acc[e] + gb[e]; m = fmaxf(m, lg[e]); }
        float p[NEXP], s = 0.f;
        for (int e = 0; e < NEXP; ++e) { p[e] = expf(lg[e] - m); s += p[e]; }
        int e0 = 0;
        for (int e = 1; e < NEXP; ++e) if (p[e] > p[e0]) e0 = e;  // strict > : first index wins ties
        int e1 = (e0 == 0) ? 1 : 0;
        for (int e = 0; e < NEXP; ++e) if (e != e0 && p[e] > p[e1]) e1 = e;
        float g0 = p[e0] / s, g1 = p[e1] / s;
        float gs = g0 + g1 + 1e-9f;
        g0 /= gs; g1 /= gs;
        tok_e[wv * 2] = e0; tok_e[wv * 2 + 1] = e1;
        tok_g[wv * 2] = g0; tok_g[wv * 2 + 1] = g1;
        atomicAdd(&counts[e0], 1);
        atomicAdd(&counts[e1], 1);
    }
}

__global__ void scan_k(const int* __restrict__ counts, int* __restrict__ base)
{
    if (threadIdx.x == 0) {
        int s = 0;
#pragma unroll
        for (int e = 0; e < NEXP; ++e) { base[e] = s; s += counts[e]; }
        base[NEXP] = s;
    }
}

__global__ __launch_bounds__(256) void scatter_k(
    const int* __restrict__ tok_e, const float* __restrict__ tok_g,
    const int* __restrict__ base, int* __restrict__ counts2,
    int* __restrict__ row_token, float* __restrict__ row_gate, int* __restrict__ tok_row)
{
    int tk = blockIdx.x * 256 + threadIdx.x;
    if (tk >= NTOK) return;
#pragma unroll
    for (int k = 0; k < 2; ++k) {
        int e = tok_e[tk * 2 + k];
        int slot = atomicAdd(&counts2[e], 1);
        int r = base[e] + slot;
        row_token[r] = tk;
        row_gate[r] = tok_g[tk * 2 + k];
        tok_row[tk * 2 + k] = r;
    }
}

// ---- batched tile transpose + fp32->bf16 conversion:
// logical src M[r][c] (r<R, row stride sld, element offset soff) -> dst bf16 [c][r] (ld=R)
// per-expert strides es (src), ed (dst). grid: (C/64, R/64, NEXP)
// XOR-swizzled tile: phase-2 gathers along r and writes 128B-contiguous segments.
__global__ __launch_bounds__(256) void transpose_k(
    const float* __restrict__ src, bf16* __restrict__ dst,
    int R, int sld, size_t soff, size_t es, size_t ed)
{
    int e = blockIdx.z;
    bf16* d = dst + (size_t)e * ed;
    __shared__ __align__(16) bf16 tile[64 * 64];
    int t = threadIdx.x;
    int r0 = blockIdx.y * 64, c0 = blockIdx.x * 64;
#pragma unroll
    for (int i = 0; i < 2; ++i) {
        int c = t + i * 256;
        int rr = c >> 3, cc = c & 7;
        size_t eo = soff + (size_t)e * es + (size_t)(r0 + rr) * sld + c0 + cc * 8;
        floatx4 a = *(const floatx4*)(src + eo);
        floatx4 b = *(const floatx4*)(src + eo + 4);
        bf16x8 v;
#pragma unroll
        for (int j = 0; j < 4; ++j) { v[j] = (bf16)a[j]; v[4 + j] = (bf16)b[j]; }
        // store chunk cc of row rr at swizzled position p = cc ^ ((rr>>3)&7)
        *(bf16x8*)&tile[rr * 64 + ((cc ^ ((rr >> 3) & 7)) * 8)] = v;
    }
    __syncthreads();
#pragma unroll
    for (int i = 0; i < 2; ++i) {
        int c = t + i * 256;
        int oc = c >> 3;       // output row (a source column), 0..63
        int occ = c & 7;       // 16B chunk along r; 8 lanes -> 128B contiguous
        bf16x8 v;
#pragma unroll
        for (int j = 0; j < 8; ++j) {
            int r = occ * 8 + j;
            int p = (oc >> 3) ^ ((r >> 3) & 7);
            v[j] = tile[r * 64 + p * 8 + (oc & 7)];
        }
        *(bf16x8*)&d[(size_t)(c0 + oc) * R + r0 + occ * 8] = v;
    }
}

// ---------------- GEMM1: h[:, chunk] = gelu(gather(xb) @ w1[e][:, chunk] + b1[e][chunk]) ------
// w1t: per-expert [Nc][DIM] bf16 (k=DIM contiguous). hbuf: [NROW][Nc] bf16. b1 fp32.
// v3: double-buffered LDS, T3-minimum 2-phase: stage(next) -> ds_read(cur) -> MFMA -> barrier.
__global__ __launch_bounds__(256) void gemm1_k(
    const bf16* __restrict__ xb, const bf16* __restrict__ w1t, const float* __restrict__ b1,
    const int* __restrict__ counts, const int* __restrict__ base,
    const int* __restrict__ row_token, bf16* __restrict__ hbuf, int Nc, int bias_off)
{
    const int e = blockIdx.z;
    const int cnt = counts[e];
    const int rt = blockIdx.y;
    if (rt * 128 >= cnt) return;
    const int rb = base[e] + rt * 128;
    const int rend = base[e] + cnt;
    const int n0 = blockIdx.x * 128;

    __shared__ __align__(16) bf16 As[2][128 * 32];
    __shared__ __align__(16) bf16 Bs[2][128 * 32];

    const int t = threadIdx.x;
    const int wv = t >> 6, lane = t & 63;
    // staging slots: slot s covers LDS 16B-chunk s = (row s>>2, pos s&3);
    // pos (s&3) holds data-chunk c = (s&3) ^ ((s>>3)&3)  [= (s&3) ^ ((row>>1)&3)]
    const int s0 = t, s1 = t + 256;
    const int ar0 = s0 >> 2, ac0 = (s0 & 3) ^ ((s0 >> 3) & 3);
    const int ar1 = s1 >> 2, ac1 = (s1 & 3) ^ ((s1 >> 3) & 3);
    int rr0 = rb + ar0; if (rr0 > NROW - 1) rr0 = NROW - 1;   // clamp: padded rows read valid data
    int rr1 = rb + ar1; if (rr1 > NROW - 1) rr1 = NROW - 1;
    const bf16* ga0 = xb + (size_t)row_token[rr0] * DIM + ac0 * 8;
    const bf16* ga1 = xb + (size_t)row_token[rr1] * DIM + ac1 * 8;
    const bf16* wb = w1t + (size_t)e * Nc * DIM;
    const bf16* gb0 = wb + (size_t)(n0 + ar0) * DIM + ac0 * 8;
    const bf16* gb1 = wb + (size_t)(n0 + ar1) * DIM + ac1 * 8;
    const int off0 = wv * 512, off1 = 2048 + wv * 512;   // wave-uniform LDS bases

    floatx4 acc[4][4];
#pragma unroll
    for (int i = 0; i < 4; ++i)
#pragma unroll
        for (int j = 0; j < 4; ++j) acc[i][j] = floatx4{0.f, 0.f, 0.f, 0.f};

    const int wr = (wv >> 1) * 64, wc = (wv & 1) * 64;
    const int lr = lane & 15;
    const int ck = lane >> 4;   // k-chunk 0..3

    // prologue: stage k0=0 into buffer 0
    gl_lds16(ga0, &As[0][off0]);
    gl_lds16(ga1, &As[0][off1]);
    gl_lds16(gb0, &Bs[0][off0]);
    gl_lds16(gb1, &Bs[0][off1]);
    __syncthreads();

    int cur = 0;
    for (int k0 = 0; k0 < DIM; k0 += 32) {
        const int kn = k0 + 32;
        if (kn < DIM) {                      // issue next tile's loads BEFORE compute
            gl_lds16(ga0 + kn, &As[cur ^ 1][off0]);
            gl_lds16(ga1 + kn, &As[cur ^ 1][off1]);
            gl_lds16(gb0 + kn, &Bs[cur ^ 1][off0]);
            gl_lds16(gb1 + kn, &Bs[cur ^ 1][off1]);
        }
        bf16x8 af[4], bg[4];
#pragma unroll
        for (int i = 0; i < 4; ++i) {
            int r = wr + i * 16 + lr;
            af[i] = *(const bf16x8*)&As[cur][r * 32 + ((ck ^ ((r >> 1) & 3)) * 8)];
        }
#pragma unroll
        for (int i = 0; i < 4; ++i) {
            int r = wc + i * 16 + lr;
            bg[i] = *(const bf16x8*)&Bs[cur][r * 32 + ((ck ^ ((r >> 1) & 3)) * 8)];
        }
#pragma unroll
        for (int mi = 0; mi < 4; ++mi)
#pragma unroll
            for (int ni = 0; ni < 4; ++ni)
                acc[mi][ni] = __builtin_amdgcn_mfma_f32_16x16x32_bf16(af[mi], bg[ni], acc[mi][ni], 0, 0, 0);
        __syncthreads();                     // drains own vmcnt -> next buffer ready for all
        cur ^= 1;
    }

#pragma unroll
    for (int mi = 0; mi < 4; ++mi) {
#pragma unroll
        for (int r = 0; r < 4; ++r) {
            int m = wr + mi * 16 + (lane >> 4) * 4 + r;  // C/D: row=(lane>>4)*4+reg, col=lane&15
            int gr = rb + m;
            if (gr < rend) {
#pragma unroll
                for (int ni = 0; ni < 4; ++ni) {
                    int col = n0 + wc + ni * 16 + lr;
                    float v = acc[mi][ni][r] + b1[e * HID + bias_off + col];
                    v = 0.5f * v * (1.f + erff(v * 0.70710678f));  // exact GELU
                    hbuf[(size_t)gr * Nc + col] = (bf16)v;
                }
            }
        }
    }
}

// ---------------- GEMM2 (split-K): ybuf += h[:, kslice] @ w2[e][kslice, :] via fp32 atomics --
// w2t: per-expert [DIM][Kc] bf16 (k=Kc contiguous). hbuf: [NROW][Kc] bf16.
// grid: (DIM/128, 32, NEXP*KSPLIT). bias+gate applied later in combine_k.
__global__ __launch_bounds__(256) void gemm2_k(
    const bf16* __restrict__ hbuf, const bf16* __restrict__ w2t,
    const int* __restrict__ counts, const int* __restrict__ base,
    float* __restrict__ ybuf, int Kc)
{
    const int e  = blockIdx.z >> 2;          // KSPLIT == 4
    const int ks = blockIdx.z & 3;
    const int cnt = counts[e];
    const int rt = blockIdx.y;
    if (rt * 128 >= cnt) return;
    const int rb = base[e] + rt * 128;
    const int rend = base[e] + cnt;
    const int n0 = blockIdx.x * 128;
    const int klen = Kc / KSPLIT;            // multiple of 32 (Kc multiple of 128)
    const int kbeg = ks * klen;

    __shared__ __align__(16) bf16 As[2][128 * 32];
    __shared__ __align__(16) bf16 Bs[2][128 * 32];

    const int t = threadIdx.x;
    const int wv = t >> 6, lane = t & 63;
    const int s0 = t, s1 = t + 256;
    const int ar0 = s0 >> 2, ac0 = (s0 & 3) ^ ((s0 >> 3) & 3);
    const int ar1 = s1 >> 2, ac1 = (s1 & 3) ^ ((s1 >> 3) & 3);
    int rr0 = rb + ar0; if (rr0 > NROW - 1) rr0 = NROW - 1;
    int rr1 = rb + ar1; if (rr1 > NROW - 1) rr1 = NROW - 1;
    const bf16* ga0 = hbuf + (size_t)rr0 * Kc + kbeg + ac0 * 8;
    const bf16* ga1 = hbuf + (size_t)rr1 * Kc + kbeg + ac1 * 8;
    const bf16* wb = w2t + (size_t)e * DIM * Kc;
    const bf16* gb0 = wb + (size_t)(n0 + ar0) * Kc + kbeg + ac0 * 8;
    const bf16* gb1 = wb + (size_t)(n0 + ar1) * Kc + kbeg + ac1 * 8;
    const int off0 = wv * 512, off1 = 2048 + wv * 512;

    floatx4 acc[4][4];
#pragma unroll
    for (int i = 0; i < 4; ++i)
#pragma unroll
        for (int j = 0; j < 4; ++j) acc[i][j] = floatx4{0.f, 0.f, 0.f, 0.f};

    const int wr = (wv >> 1) * 64, wc = (wv & 1) * 64;
    const int lr = lane & 15;
    const int ck = lane >> 4;

    gl_lds16(ga0, &As[0][off0]);
    gl_lds16(ga1, &As[0][off1]);
    gl_lds16(gb0, &Bs[0][off0]);
    gl_lds16(gb1, &Bs[0][off1]);
    __syncthreads();

    int cur = 0;
    for (int k0 = 0; k0 < klen; k0 += 32) {
        const int kn = k0 + 32;
        if (kn < klen) {
            gl_lds16(ga0 + kn, &As[cur ^ 1][off0]);
            gl_lds16(ga1 + kn, &As[cur ^ 1][off1]);
            gl_lds16(gb0 + kn, &Bs[cur ^ 1][off0]);
            gl_lds16(gb1 + kn, &Bs[cur ^ 1][off1]);
        }
        bf16x8 af[4], bg[4];
#pragma unroll
        for (int i = 0; i < 4; ++i) {
            int r = wr + i * 16 + lr;
            af[i] = *(const bf16x8*)&As[cur][r * 32 + ((ck ^ ((r >> 1) & 3)) * 8)];
        }
#pragma unroll
        for (int i = 0; i < 4; ++i) {
            int r = wc + i * 16 + lr;
            bg[i] = *(const bf16x8*)&Bs[cur][r * 32 + ((ck ^ ((r >> 1) & 3)) * 8)];
        }
#pragma unroll
        for (int mi = 0; mi < 4; ++mi)
#pragma unroll
            for (int ni = 0; ni < 4; ++ni)
                acc[mi][ni] = __builtin_amdgcn_mfma_f32_16x16x32_bf16(af[mi], bg[ni], acc[mi][ni], 0, 0, 0);
        __syncthreads();
        cur ^= 1;
    }

#pragma unroll
    for (int mi = 0; mi < 4; ++mi) {
#pragma unroll
        for (int r = 0; r < 4; ++r) {
            int m = wr + mi * 16 + (lane >> 4) * 4 + r;
            int gr = rb + m;
            if (gr < rend) {
#pragma unroll
                for (int ni = 0; ni < 4; ++ni) {
                    int col = n0 + wc + ni * 16 + lr;
                    atomicAdd(&ybuf[(size_t)gr * DIM + col], acc[mi][ni][r]);
                }
            }
        }
    }
}

// ---------------- combine: out[t] = Σ_k g_k * (ybuf[row_k] + b2[e_k]), fp32 out --------------
__global__ __launch_bounds__(256) void combine_k(
    const float* __restrict__ ybuf, const int* __restrict__ tok_row,
    const int* __restrict__ tok_e, const float* __restrict__ tok_g,
    const float* __restrict__ b2, float* __restrict__ out)
{
    int i = blockIdx.x * 256 + threadIdx.x;
    int tk = i >> 8;            // DIM/4 == 256 chunks per token
    int dc = (i & 255) * 4;
    int ra = tok_row[tk * 2], rbx = tok_row[tk * 2 + 1];
    int ea = tok_e[tk * 2],  eb = tok_e[tk * 2 + 1];
    float ga = tok_g[tk * 2], gbv = tok_g[tk * 2 + 1];
    floatx4 a  = *(const floatx4*)&ybuf[(size_t)ra * DIM + dc];
    floatx4 b  = *(const floatx4*)&ybuf[(size_t)rbx * DIM + dc];
    floatx4 b2a = *(const floatx4*)&b2[ea * DIM + dc];
    floatx4 b2b = *(const floatx4*)&b2[eb * DIM + dc];
    floatx4 o;
#pragma unroll
    for (int j = 0; j < 4; ++j) o[j] = ga * (a[j] + b2a[j]) + gbv * (b[j] + b2b[j]);
    *(floatx4*)&out[(size_t)tk * DIM + dc] = o;
}

extern "C" void kernel_launch(void* const* d_in, const int* in_sizes, int n_in,
                              void* d_out, int out_size, void* d_ws, size_t ws_size,
                              hipStream_t stream)
{
    const float* x  = (const float*)d_in[0];
    const float* gw = (const float*)d_in[1];
    const float* gb = (const float*)d_in[2];
    const float* w1 = (const float*)d_in[3];
    const float* b1 = (const float*)d_in[4];
    const float* w2 = (const float*)d_in[5];
    const float* b2 = (const float*)d_in[6];
    float* out = (float*)d_out;

    char* w = (char*)d_ws;
    int*   counts  = (int*)(w + 0);        // 8 ints
    int*   counts2 = (int*)(w + 32);       // 8 ints
    int*   base    = (int*)(w + 64);       // 9 ints
    int*   tok_e   = (int*)(w + 256);
    float* tok_g   = (float*)(w + 256 + 32768);
    int*   row_tok = (int*)(w + 256 + 2 * 32768);
    float* row_g   = (float*)(w + 256 + 3 * 32768);
    int*   tok_row = (int*)(w + 256 + 4 * 32768);
    size_t off = 256 + 5 * 32768;                                       // 256-aligned
    bf16*  xb   = (bf16*)(w + off);   off += (size_t)NTOK * DIM * 2;    // 8 MiB
    float* ybuf = (float*)(w + off);  off += (size_t)NROW * DIM * 4;    // 32 MiB

    // choose H-chunk so total footprint fits ws_size (deterministic across calls)
    int Hc = HID;
    for (;;) {
        size_t need = off + (size_t)NEXP * Hc * DIM * 2 + (size_t)NROW * Hc * 2;
        if (need <= ws_size || Hc == 128) break;
        Hc >>= 1;
    }
    bf16* wT   = (bf16*)(w + off);  off += (size_t)NEXP * Hc * DIM * 2;  // per chunk: w1^T slice, then w2^T slice
    bf16* hbuf = (bf16*)(w + off);                                       // [NROW][Hc]

    zero_k<<<1, 64, 0, stream>>>(counts);
    router_k<<<NTOK / 4, 256, 0, stream>>>(x, gw, gb, counts, tok_e, tok_g);
    scan_k<<<1, 64, 0, stream>>>(counts, base);
    scatter_k<<<NTOK / 256, 256, 0, stream>>>(tok_e, tok_g, base, counts2, row_tok, row_g, tok_row);
    convx_k<<<(NTOK * DIM) / 2048, 256, 0, stream>>>(x, xb);
    zeroy_k<<<(NROW * DIM) / 1024, 256, 0, stream>>>(ybuf);   // split-K accumulator

    const int nc = HID / Hc;
    for (int ch = 0; ch < nc; ++ch) {
        // w1[e] cols [ch*Hc, +Hc): logical [DIM][Hc] row-stride HID -> wT [Hc][DIM]
        transpose_k<<<dim3(Hc / 64, DIM / 64, NEXP), 256, 0, stream>>>(
            w1, wT, DIM, HID, (size_t)ch * Hc, (size_t)DIM * HID, (size_t)Hc * DIM);
        gemm1_k<<<dim3(Hc / 128, 32, NEXP), 256, 0, stream>>>(
            xb, wT, b1, counts, base, row_tok, hbuf, Hc, ch * Hc);
        // w2[e] rows [ch*Hc, +Hc): logical [Hc][DIM] contiguous -> wT [DIM][Hc]
        transpose_k<<<dim3(DIM / 64, Hc / 64, NEXP), 256, 0, stream>>>(
            w2, wT, Hc, DIM, (size_t)ch * Hc * DIM, (size_t)HID * DIM, (size_t)DIM * Hc);
        gemm2_k<<<dim3(DIM / 128, 32, NEXP * KSPLIT), 256, 0, stream>>>(
            hbuf, wT, counts, base, ybuf, Hc);
    }

    combine_k<<<NTOK, 256, 0, stream>>>(ybuf, tok_row, tok_e, tok_g, b2, out);
}

// Round 3
// 741.634 us; speedup vs baseline: 1.0315x; 1.0315x over previous
//
#include <hip/hip_runtime.h>
#include <math.h>

#define NTOK 4096   // B*T tokens
#define DIM  1024
#define HID  4096
#define NEXP 8
#define NROW 8192   // NTOK * K (top-2): every token occupies exactly 2 rows

typedef __bf16 bf16;
typedef __attribute__((ext_vector_type(8))) __bf16 bf16x8;
typedef __attribute__((ext_vector_type(4))) float floatx4;

// async global->LDS, 16B per lane. LDS dest is wave-uniform base + lane*16.
__device__ __forceinline__ void gl_lds16(const bf16* g, bf16* l) {
    __builtin_amdgcn_global_load_lds(
        (const __attribute__((address_space(1))) void*)g,
        (__attribute__((address_space(3))) void*)l, 16, 0, 0);
}

__global__ void zero_k(int* __restrict__ p) {
    if (threadIdx.x < 16) p[threadIdx.x] = 0;   // counts[8] + counts2[8]
}

// ---- convert x (fp32) -> bf16 xb for the MFMA path
__global__ __launch_bounds__(256) void convx_k(const float* __restrict__ x,
                                               bf16* __restrict__ xb)
{
    size_t gid = (size_t)blockIdx.x * 256 + threadIdx.x;
    size_t eo = gid * 8;
    floatx4 a = *(const floatx4*)(x + eo);
    floatx4 b = *(const floatx4*)(x + eo + 4);
    bf16x8 v;
#pragma unroll
    for (int j = 0; j < 4; ++j) { v[j] = (bf16)a[j]; v[4 + j] = (bf16)b[j]; }
    *(bf16x8*)&xb[eo] = v;
}

// ---------------- router: one wave per token, FULL FP32 (top-k must match np ref exactly) ----
__global__ __launch_bounds__(256) void router_k(
    const float* __restrict__ x, const float* __restrict__ gw, const float* __restrict__ gb,
    int* __restrict__ counts, int* __restrict__ tok_e, float* __restrict__ tok_g)
{
    __shared__ __align__(16) float gws[DIM * NEXP];   // 32 KB fp32
    int t = threadIdx.x;
#pragma unroll
    for (int i = 0; i < 8; ++i)
        *(floatx4*)&gws[(t * 8 + i) * 4] = *(const floatx4*)&gw[(t * 8 + i) * 4];
    __syncthreads();

    int gid = blockIdx.x * 256 + t;
    int wv = gid >> 6, lane = gid & 63;       // grid covers exactly NTOK waves
    const float* xr = x + (size_t)wv * DIM;
    float acc[NEXP];
#pragma unroll
    for (int e = 0; e < NEXP; ++e) acc[e] = 0.f;
    int d0 = lane * 16;
#pragma unroll
    for (int j = 0; j < 16; ++j) {
        float xv = xr[d0 + j];
#pragma unroll
        for (int e = 0; e < NEXP; ++e) acc[e] += xv * gws[(d0 + j) * NEXP + e];
    }
#pragma unroll
    for (int off = 32; off > 0; off >>= 1) {
#pragma unroll
        for (int e = 0; e < NEXP; ++e) acc[e] += __shfl_xor(acc[e], off, 64);
    }
    if (lane == 0) {
        float lg[NEXP], m = -1e30f;
        for (int e = 0; e < NEXP; ++e) { lg[e] = acc[e] + gb[e]; m = fmaxf(m, lg[e]); }
        float p[NEXP], s = 0.f;
        for (int e = 0; e < NEXP; ++e) { p[e] = expf(lg[e] - m); s += p[e]; }
        int e0 = 0;
        for (int e = 1; e < NEXP; ++e) if (p[e] > p[e0]) e0 = e;  // strict > : first index wins ties
        int e1 = (e0 == 0) ? 1 : 0;
        for (int e = 0; e < NEXP; ++e) if (e != e0 && p[e] > p[e1]) e1 = e;
        float g0 = p[e0] / s, g1 = p[e1] / s;
        float gs = g0 + g1 + 1e-9f;
        g0 /= gs; g1 /= gs;
        tok_e[wv * 2] = e0; tok_e[wv * 2 + 1] = e1;
        tok_g[wv * 2] = g0; tok_g[wv * 2 + 1] = g1;
        atomicAdd(&counts[e0], 1);
        atomicAdd(&counts[e1], 1);
    }
}

__global__ void scan_k(const int* __restrict__ counts, int* __restrict__ base)
{
    if (threadIdx.x == 0) {
        int s = 0;
#pragma unroll
        for (int e = 0; e < NEXP; ++e) { base[e] = s; s += counts[e]; }
        base[NEXP] = s;
    }
}

__global__ __launch_bounds__(256) void scatter_k(
    const int* __restrict__ tok_e, const float* __restrict__ tok_g,
    const int* __restrict__ base, int* __restrict__ counts2,
    int* __restrict__ row_token, float* __restrict__ row_gate, int* __restrict__ tok_row)
{
    int tk = blockIdx.x * 256 + threadIdx.x;
    if (tk >= NTOK) return;
#pragma unroll
    for (int k = 0; k < 2; ++k) {
        int e = tok_e[tk * 2 + k];
        int slot = atomicAdd(&counts2[e], 1);
        int r = base[e] + slot;
        row_token[r] = tk;
        row_gate[r] = tok_g[tk * 2 + k];
        tok_row[tk * 2 + k] = r;
    }
}

// ---- batched tile transpose + fp32->bf16 conversion:
// logical src M[r][c] (r<R, row stride sld, element offset soff) -> dst bf16 [c][r] (ld=R)
// per-expert strides es (src), ed (dst). grid: (C/64, R/64, NEXP)
// XOR-swizzled tile: phase-2 gathers along r and writes 128B-contiguous segments.
__global__ __launch_bounds__(256) void transpose_k(
    const float* __restrict__ src, bf16* __restrict__ dst,
    int R, int sld, size_t soff, size_t es, size_t ed)
{
    int e = blockIdx.z;
    bf16* d = dst + (size_t)e * ed;
    __shared__ __align__(16) bf16 tile[64 * 64];
    int t = threadIdx.x;
    int r0 = blockIdx.y * 64, c0 = blockIdx.x * 64;
#pragma unroll
    for (int i = 0; i < 2; ++i) {
        int c = t + i * 256;
        int rr = c >> 3, cc = c & 7;
        size_t eo = soff + (size_t)e * es + (size_t)(r0 + rr) * sld + c0 + cc * 8;
        floatx4 a = *(const floatx4*)(src + eo);
        floatx4 b = *(const floatx4*)(src + eo + 4);
        bf16x8 v;
#pragma unroll
        for (int j = 0; j < 4; ++j) { v[j] = (bf16)a[j]; v[4 + j] = (bf16)b[j]; }
        // store chunk cc of row rr at swizzled position p = cc ^ ((rr>>3)&7)
        *(bf16x8*)&tile[rr * 64 + ((cc ^ ((rr >> 3) & 7)) * 8)] = v;
    }
    __syncthreads();
#pragma unroll
    for (int i = 0; i < 2; ++i) {
        int c = t + i * 256;
        int oc = c >> 3;       // output row (a source column), 0..63
        int occ = c & 7;       // 16B chunk along r; 8 lanes -> 128B contiguous
        bf16x8 v;
#pragma unroll
        for (int j = 0; j < 8; ++j) {
            int r = occ * 8 + j;
            int p = (oc >> 3) ^ ((r >> 3) & 7);
            v[j] = tile[r * 64 + p * 8 + (oc & 7)];
        }
        *(bf16x8*)&d[(size_t)(c0 + oc) * R + r0 + occ * 8] = v;
    }
}

// ---------------- GEMM1: h[:, chunk] = gelu(gather(xb) @ w1[e][:, chunk] + b1[e][chunk]) ------
// w1t: per-expert [Nc][DIM] bf16 (k=DIM contiguous). hbuf: [NROW][Nc] bf16. b1 fp32.
// v4: 3-buffer depth-2 pipeline, counted vmcnt(4) (T4), raw s_barrier, setprio (T5).
__global__ __launch_bounds__(256) void gemm1_k(
    const bf16* __restrict__ xb, const bf16* __restrict__ w1t, const float* __restrict__ b1,
    const int* __restrict__ counts, const int* __restrict__ base,
    const int* __restrict__ row_token, bf16* __restrict__ hbuf, int Nc, int bias_off)
{
    const int e = blockIdx.z;
    const int cnt = counts[e];
    const int rt = blockIdx.y;
    if (rt * 128 >= cnt) return;
    const int rb = base[e] + rt * 128;
    const int rend = base[e] + cnt;
    const int n0 = blockIdx.x * 128;

    __shared__ __align__(16) bf16 As[3][128 * 32];   // 3 x 8 KB
    __shared__ __align__(16) bf16 Bs[3][128 * 32];   // 3 x 8 KB

    const int t = threadIdx.x;
    const int wv = t >> 6, lane = t & 63;
    // staging slots: slot s covers LDS 16B-chunk s = (row s>>2, pos s&3);
    // pos (s&3) holds data-chunk c = (s&3) ^ ((s>>3)&3)  [= (s&3) ^ ((row>>1)&3)]
    const int s0 = t, s1 = t + 256;
    const int ar0 = s0 >> 2, ac0 = (s0 & 3) ^ ((s0 >> 3) & 3);
    const int ar1 = s1 >> 2, ac1 = (s1 & 3) ^ ((s1 >> 3) & 3);
    int rr0 = rb + ar0; if (rr0 > NROW - 1) rr0 = NROW - 1;   // clamp: padded rows read valid data
    int rr1 = rb + ar1; if (rr1 > NROW - 1) rr1 = NROW - 1;
    const bf16* ga0 = xb + (size_t)row_token[rr0] * DIM + ac0 * 8;
    const bf16* ga1 = xb + (size_t)row_token[rr1] * DIM + ac1 * 8;
    const bf16* wb = w1t + (size_t)e * Nc * DIM;
    const bf16* gb0 = wb + (size_t)(n0 + ar0) * DIM + ac0 * 8;
    const bf16* gb1 = wb + (size_t)(n0 + ar1) * DIM + ac1 * 8;
    const int off0 = wv * 512, off1 = 2048 + wv * 512;   // wave-uniform LDS bases

    floatx4 acc[4][4];
#pragma unroll
    for (int i = 0; i < 4; ++i)
#pragma unroll
        for (int j = 0; j < 4; ++j) acc[i][j] = floatx4{0.f, 0.f, 0.f, 0.f};

    const int wr = (wv >> 1) * 64, wc = (wv & 1) * 64;
    const int lr = lane & 15;
    const int ck = lane >> 4;   // k-chunk 0..3

    // prologue: stage steps 0,1 into buffers 0,1
    gl_lds16(ga0,      &As[0][off0]); gl_lds16(ga1,      &As[0][off1]);
    gl_lds16(gb0,      &Bs[0][off0]); gl_lds16(gb1,      &Bs[0][off1]);
    gl_lds16(ga0 + 32, &As[1][off0]); gl_lds16(ga1 + 32, &As[1][off1]);
    gl_lds16(gb0 + 32, &Bs[1][off0]); gl_lds16(gb1 + 32, &Bs[1][off1]);

    const int NSTEP = DIM / 32;   // 32
    int bc = 0;                   // current buffer (i % 3)
    for (int i = 0; i < NSTEP; ++i) {
        // counted wait: allow the newest 4 loads (stage i+1) in flight; stage i retired.
        if (i < NSTEP - 1) asm volatile("s_waitcnt vmcnt(4)" ::: "memory");
        else               asm volatile("s_waitcnt vmcnt(0)" ::: "memory");
        __builtin_amdgcn_s_barrier();          // all waves: stage(i) visible in LDS
        asm volatile("" ::: "memory");
        if (i + 2 < NSTEP) {                   // issue stage(i+2) into buf (i+2)%3
            int bs = bc + 2; if (bs >= 3) bs -= 3;
            const int kn = (i + 2) * 32;
            gl_lds16(ga0 + kn, &As[bs][off0]); gl_lds16(ga1 + kn, &As[bs][off1]);
            gl_lds16(gb0 + kn, &Bs[bs][off0]); gl_lds16(gb1 + kn, &Bs[bs][off1]);
        }
        bf16x8 af[4], bg[4];
#pragma unroll
        for (int q = 0; q < 4; ++q) {
            int r = wr + q * 16 + lr;
            af[q] = *(const bf16x8*)&As[bc][r * 32 + ((ck ^ ((r >> 1) & 3)) * 8)];
        }
#pragma unroll
        for (int q = 0; q < 4; ++q) {
            int r = wc + q * 16 + lr;
            bg[q] = *(const bf16x8*)&Bs[bc][r * 32 + ((ck ^ ((r >> 1) & 3)) * 8)];
        }
        __builtin_amdgcn_s_setprio(1);
#pragma unroll
        for (int mi = 0; mi < 4; ++mi)
#pragma unroll
            for (int ni = 0; ni < 4; ++ni)
                acc[mi][ni] = __builtin_amdgcn_mfma_f32_16x16x32_bf16(af[mi], bg[ni], acc[mi][ni], 0, 0, 0);
        __builtin_amdgcn_s_setprio(0);
        bc += 1; if (bc >= 3) bc -= 3;
    }

#pragma unroll
    for (int mi = 0; mi < 4; ++mi) {
#pragma unroll
        for (int r = 0; r < 4; ++r) {
            int m = wr + mi * 16 + (lane >> 4) * 4 + r;  // C/D: row=(lane>>4)*4+reg, col=lane&15
            int gr = rb + m;
            if (gr < rend) {
#pragma unroll
                for (int ni = 0; ni < 4; ++ni) {
                    int col = n0 + wc + ni * 16 + lr;
                    float v = acc[mi][ni][r] + b1[e * HID + bias_off + col];
                    v = 0.5f * v * (1.f + erff(v * 0.70710678f));  // exact GELU
                    hbuf[(size_t)gr * Nc + col] = (bf16)v;
                }
            }
        }
    }
}

// ---------------- GEMM2: y += h[:, chunk] @ w2[e][chunk, :]; last chunk applies bias+gate -----
// w2t: per-expert [DIM][Kc] bf16 (k=Kc contiguous). hbuf: [NROW][Kc] bf16. ybuf fp32. b2 fp32.
// v4: same 3-buffer counted-vmcnt pipeline; no split-K, no atomics.
__global__ __launch_bounds__(256) void gemm2_k(
    const bf16* __restrict__ hbuf, const bf16* __restrict__ w2t, const float* __restrict__ b2,
    const int* __restrict__ counts, const int* __restrict__ base,
    const float* __restrict__ row_gate, float* __restrict__ ybuf,
    int Kc, int first, int last)
{
    const int e = blockIdx.z;
    const int cnt = counts[e];
    const int rt = blockIdx.y;
    if (rt * 128 >= cnt) return;
    const int rb = base[e] + rt * 128;
    const int rend = base[e] + cnt;
    const int n0 = blockIdx.x * 128;

    __shared__ __align__(16) bf16 As[3][128 * 32];
    __shared__ __align__(16) bf16 Bs[3][128 * 32];

    const int t = threadIdx.x;
    const int wv = t >> 6, lane = t & 63;
    const int s0 = t, s1 = t + 256;
    const int ar0 = s0 >> 2, ac0 = (s0 & 3) ^ ((s0 >> 3) & 3);
    const int ar1 = s1 >> 2, ac1 = (s1 & 3) ^ ((s1 >> 3) & 3);
    int rr0 = rb + ar0; if (rr0 > NROW - 1) rr0 = NROW - 1;
    int rr1 = rb + ar1; if (rr1 > NROW - 1) rr1 = NROW - 1;
    const bf16* ga0 = hbuf + (size_t)rr0 * Kc + ac0 * 8;
    const bf16* ga1 = hbuf + (size_t)rr1 * Kc + ac1 * 8;
    const bf16* wb = w2t + (size_t)e * DIM * Kc;
    const bf16* gb0 = wb + (size_t)(n0 + ar0) * Kc + ac0 * 8;
    const bf16* gb1 = wb + (size_t)(n0 + ar1) * Kc + ac1 * 8;
    const int off0 = wv * 512, off1 = 2048 + wv * 512;

    floatx4 acc[4][4];
#pragma unroll
    for (int i = 0; i < 4; ++i)
#pragma unroll
        for (int j = 0; j < 4; ++j) acc[i][j] = floatx4{0.f, 0.f, 0.f, 0.f};

    const int wr = (wv >> 1) * 64, wc = (wv & 1) * 64;
    const int lr = lane & 15;
    const int ck = lane >> 4;

    gl_lds16(ga0,      &As[0][off0]); gl_lds16(ga1,      &As[0][off1]);
    gl_lds16(gb0,      &Bs[0][off0]); gl_lds16(gb1,      &Bs[0][off1]);
    gl_lds16(ga0 + 32, &As[1][off0]); gl_lds16(ga1 + 32, &As[1][off1]);
    gl_lds16(gb0 + 32, &Bs[1][off0]); gl_lds16(gb1 + 32, &Bs[1][off1]);

    const int nstep = Kc >> 5;
    int bc = 0;
    for (int i = 0; i < nstep; ++i) {
        if (i < nstep - 1) asm volatile("s_waitcnt vmcnt(4)" ::: "memory");
        else               asm volatile("s_waitcnt vmcnt(0)" ::: "memory");
        __builtin_amdgcn_s_barrier();
        asm volatile("" ::: "memory");
        if (i + 2 < nstep) {
            int bs = bc + 2; if (bs >= 3) bs -= 3;
            const int kn = (i + 2) * 32;
            gl_lds16(ga0 + kn, &As[bs][off0]); gl_lds16(ga1 + kn, &As[bs][off1]);
            gl_lds16(gb0 + kn, &Bs[bs][off0]); gl_lds16(gb1 + kn, &Bs[bs][off1]);
        }
        bf16x8 af[4], bg[4];
#pragma unroll
        for (int q = 0; q < 4; ++q) {
            int r = wr + q * 16 + lr;
            af[q] = *(const bf16x8*)&As[bc][r * 32 + ((ck ^ ((r >> 1) & 3)) * 8)];
        }
#pragma unroll
        for (int q = 0; q < 4; ++q) {
            int r = wc + q * 16 + lr;
            bg[q] = *(const bf16x8*)&Bs[bc][r * 32 + ((ck ^ ((r >> 1) & 3)) * 8)];
        }
        __builtin_amdgcn_s_setprio(1);
#pragma unroll
        for (int mi = 0; mi < 4; ++mi)
#pragma unroll
            for (int ni = 0; ni < 4; ++ni)
                acc[mi][ni] = __builtin_amdgcn_mfma_f32_16x16x32_bf16(af[mi], bg[ni], acc[mi][ni], 0, 0, 0);
        __builtin_amdgcn_s_setprio(0);
        bc += 1; if (bc >= 3) bc -= 3;
    }

#pragma unroll
    for (int mi = 0; mi < 4; ++mi) {
#pragma unroll
        for (int r = 0; r < 4; ++r) {
            int m = wr + mi * 16 + (lane >> 4) * 4 + r;
            int gr = rb + m;
            if (gr < rend) {
#pragma unroll
                for (int ni = 0; ni < 4; ++ni) {
                    int col = n0 + wc + ni * 16 + lr;
                    size_t idx = (size_t)gr * DIM + col;
                    float v = acc[mi][ni][r];
                    if (last) {
                        float prev = first ? 0.f : ybuf[idx];
                        ybuf[idx] = row_gate[gr] * (prev + v + b2[e * DIM + col]);
                    } else {
                        ybuf[idx] = first ? v : (ybuf[idx] + v);
                    }
                }
            }
        }
    }
}

// ---------------- combine: out[t] = y[row(t,0)] + y[row(t,1)], fp32 out ----------------
__global__ __launch_bounds__(256) void combine_k(
    const float* __restrict__ ybuf, const int* __restrict__ tok_row, float* __restrict__ out)
{
    int i = blockIdx.x * 256 + threadIdx.x;
    int tk = i >> 8;            // DIM/4 == 256 chunks per token
    int dc = (i & 255) * 4;
    int ra = tok_row[tk * 2], rb = tok_row[tk * 2 + 1];
    floatx4 a = *(const floatx4*)&ybuf[(size_t)ra * DIM + dc];
    floatx4 b = *(const floatx4*)&ybuf[(size_t)rb * DIM + dc];
    floatx4 o;
#pragma unroll
    for (int j = 0; j < 4; ++j) o[j] = a[j] + b[j];
    *(floatx4*)&out[(size_t)tk * DIM + dc] = o;
}

extern "C" void kernel_launch(void* const* d_in, const int* in_sizes, int n_in,
                              void* d_out, int out_size, void* d_ws, size_t ws_size,
                              hipStream_t stream)
{
    const float* x  = (const float*)d_in[0];
    const float* gw = (const float*)d_in[1];
    const float* gb = (const float*)d_in[2];
    const float* w1 = (const float*)d_in[3];
    const float* b1 = (const float*)d_in[4];
    const float* w2 = (const float*)d_in[5];
    const float* b2 = (const float*)d_in[6];
    float* out = (float*)d_out;

    char* w = (char*)d_ws;
    int*   counts  = (int*)(w + 0);        // 8 ints
    int*   counts2 = (int*)(w + 32);       // 8 ints
    int*   base    = (int*)(w + 64);       // 9 ints
    int*   tok_e   = (int*)(w + 256);
    float* tok_g   = (float*)(w + 256 + 32768);
    int*   row_tok = (int*)(w + 256 + 2 * 32768);
    float* row_g   = (float*)(w + 256 + 3 * 32768);
    int*   tok_row = (int*)(w + 256 + 4 * 32768);
    size_t off = 256 + 5 * 32768;                                       // 256-aligned
    bf16*  xb   = (bf16*)(w + off);   off += (size_t)NTOK * DIM * 2;    // 8 MiB
    float* ybuf = (float*)(w + off);  off += (size_t)NROW * DIM * 4;    // 32 MiB

    // choose H-chunk so total footprint fits ws_size (deterministic across calls)
    int Hc = HID;
    for (;;) {
        size_t need = off + (size_t)NEXP * Hc * DIM * 2 + (size_t)NROW * Hc * 2;
        if (need <= ws_size || Hc == 128) break;
        Hc >>= 1;
    }
    bf16* wT   = (bf16*)(w + off);  off += (size_t)NEXP * Hc * DIM * 2;  // per chunk: w1^T slice, then w2^T slice
    bf16* hbuf = (bf16*)(w + off);                                       // [NROW][Hc]

    zero_k<<<1, 64, 0, stream>>>(counts);
    router_k<<<NTOK / 4, 256, 0, stream>>>(x, gw, gb, counts, tok_e, tok_g);
    scan_k<<<1, 64, 0, stream>>>(counts, base);
    scatter_k<<<NTOK / 256, 256, 0, stream>>>(tok_e, tok_g, base, counts2, row_tok, row_g, tok_row);
    convx_k<<<(NTOK * DIM) / 2048, 256, 0, stream>>>(x, xb);

    const int nc = HID / Hc;
    for (int ch = 0; ch < nc; ++ch) {
        // w1[e] cols [ch*Hc, +Hc): logical [DIM][Hc] row-stride HID -> wT [Hc][DIM]
        transpose_k<<<dim3(Hc / 64, DIM / 64, NEXP), 256, 0, stream>>>(
            w1, wT, DIM, HID, (size_t)ch * Hc, (size_t)DIM * HID, (size_t)Hc * DIM);
        gemm1_k<<<dim3(Hc / 128, 32, NEXP), 256, 0, stream>>>(
            xb, wT, b1, counts, base, row_tok, hbuf, Hc, ch * Hc);
        // w2[e] rows [ch*Hc, +Hc): logical [Hc][DIM] contiguous -> wT [DIM][Hc]
        transpose_k<<<dim3(DIM / 64, Hc / 64, NEXP), 256, 0, stream>>>(
            w2, wT, Hc, DIM, (size_t)ch * Hc * DIM, (size_t)HID * DIM, (size_t)DIM * Hc);
        gemm2_k<<<dim3(DIM / 128, 32, NEXP), 256, 0, stream>>>(
            hbuf, wT, b2, counts, base, row_g, ybuf, Hc, ch == 0, ch == nc - 1);
    }

    combine_k<<<NTOK, 256, 0, stream>>>(ybuf, tok_row, out);
}

// Round 4
// 723.109 us; speedup vs baseline: 1.0579x; 1.0256x over previous
//
#include <hip/hip_runtime.h>
#include <math.h>

#define NTOK 4096   // B*T tokens
#define DIM  1024
#define HID  4096
#define NEXP 8
#define NROW 8192   // NTOK * K (top-2): every token occupies exactly 2 rows
#define KSPLIT 2    // non-atomic split-K for gemm2: separate ybuf slices, summed in combine

typedef __bf16 bf16;
typedef __attribute__((ext_vector_type(8))) __bf16 bf16x8;
typedef __attribute__((ext_vector_type(4))) float floatx4;

// async global->LDS, 16B per lane. LDS dest is wave-uniform base + lane*16.
__device__ __forceinline__ void gl_lds16(const bf16* g, bf16* l) {
    __builtin_amdgcn_global_load_lds(
        (const __attribute__((address_space(1))) void*)g,
        (__attribute__((address_space(3))) void*)l, 16, 0, 0);
}

__global__ void zero_k(int* __restrict__ p) {
    if (threadIdx.x < 16) p[threadIdx.x] = 0;   // counts[8] + counts2[8]
}

// ---- convert x (fp32) -> bf16 xb for the MFMA path
__global__ __launch_bounds__(256) void convx_k(const float* __restrict__ x,
                                               bf16* __restrict__ xb)
{
    size_t gid = (size_t)blockIdx.x * 256 + threadIdx.x;
    size_t eo = gid * 8;
    floatx4 a = *(const floatx4*)(x + eo);
    floatx4 b = *(const floatx4*)(x + eo + 4);
    bf16x8 v;
#pragma unroll
    for (int j = 0; j < 4; ++j) { v[j] = (bf16)a[j]; v[4 + j] = (bf16)b[j]; }
    *(bf16x8*)&xb[eo] = v;
}

// ---------------- router: one wave per token, FULL FP32 (top-k must match np ref exactly) ----
__global__ __launch_bounds__(256) void router_k(
    const float* __restrict__ x, const float* __restrict__ gw, const float* __restrict__ gb,
    int* __restrict__ counts, int* __restrict__ tok_e, float* __restrict__ tok_g)
{
    __shared__ __align__(16) float gws[DIM * NEXP];   // 32 KB fp32
    int t = threadIdx.x;
#pragma unroll
    for (int i = 0; i < 8; ++i)
        *(floatx4*)&gws[(t * 8 + i) * 4] = *(const floatx4*)&gw[(t * 8 + i) * 4];
    __syncthreads();

    int gid = blockIdx.x * 256 + t;
    int wv = gid >> 6, lane = gid & 63;       // grid covers exactly NTOK waves
    const float* xr = x + (size_t)wv * DIM;
    float acc[NEXP];
#pragma unroll
    for (int e = 0; e < NEXP; ++e) acc[e] = 0.f;
    int d0 = lane * 16;
#pragma unroll
    for (int j = 0; j < 16; ++j) {
        float xv = xr[d0 + j];
#pragma unroll
        for (int e = 0; e < NEXP; ++e) acc[e] += xv * gws[(d0 + j) * NEXP + e];
    }
#pragma unroll
    for (int off = 32; off > 0; off >>= 1) {
#pragma unroll
        for (int e = 0; e < NEXP; ++e) acc[e] += __shfl_xor(acc[e], off, 64);
    }
    if (lane == 0) {
        float lg[NEXP], m = -1e30f;
        for (int e = 0; e < NEXP; ++e) { lg[e] = acc[e] + gb[e]; m = fmaxf(m, lg[e]); }
        float p[NEXP], s = 0.f;
        for (int e = 0; e < NEXP; ++e) { p[e] = expf(lg[e] - m); s += p[e]; }
        int e0 = 0;
        for (int e = 1; e < NEXP; ++e) if (p[e] > p[e0]) e0 = e;  // strict > : first index wins ties
        int e1 = (e0 == 0) ? 1 : 0;
        for (int e = 0; e < NEXP; ++e) if (e != e0 && p[e] > p[e1]) e1 = e;
        float g0 = p[e0] / s, g1 = p[e1] / s;
        float gs = g0 + g1 + 1e-9f;
        g0 /= gs; g1 /= gs;
        tok_e[wv * 2] = e0; tok_e[wv * 2 + 1] = e1;
        tok_g[wv * 2] = g0; tok_g[wv * 2 + 1] = g1;
        atomicAdd(&counts[e0], 1);
        atomicAdd(&counts[e1], 1);
    }
}

__global__ void scan_k(const int* __restrict__ counts, int* __restrict__ base)
{
    if (threadIdx.x == 0) {
        int s = 0;
#pragma unroll
        for (int e = 0; e < NEXP; ++e) { base[e] = s; s += counts[e]; }
        base[NEXP] = s;
    }
}

__global__ __launch_bounds__(256) void scatter_k(
    const int* __restrict__ tok_e, const float* __restrict__ tok_g,
    const int* __restrict__ base, int* __restrict__ counts2,
    int* __restrict__ row_token, float* __restrict__ row_gate, int* __restrict__ tok_row)
{
    int tk = blockIdx.x * 256 + threadIdx.x;
    if (tk >= NTOK) return;
#pragma unroll
    for (int k = 0; k < 2; ++k) {
        int e = tok_e[tk * 2 + k];
        int slot = atomicAdd(&counts2[e], 1);
        int r = base[e] + slot;
        row_token[r] = tk;
        row_gate[r] = tok_g[tk * 2 + k];
        tok_row[tk * 2 + k] = r;
    }
}

// ---- batched tile transpose + fp32->bf16 conversion:
// logical src M[r][c] (r<R, row stride sld, element offset soff) -> dst bf16 [c][r] (ld=R)
// per-expert strides es (src), ed (dst). grid: (C/64, R/64, NEXP)
// XOR-swizzled tile: phase-2 gathers along r and writes 128B-contiguous segments.
__global__ __launch_bounds__(256) void transpose_k(
    const float* __restrict__ src, bf16* __restrict__ dst,
    int R, int sld, size_t soff, size_t es, size_t ed)
{
    int e = blockIdx.z;
    bf16* d = dst + (size_t)e * ed;
    __shared__ __align__(16) bf16 tile[64 * 64];
    int t = threadIdx.x;
    int r0 = blockIdx.y * 64, c0 = blockIdx.x * 64;
#pragma unroll
    for (int i = 0; i < 2; ++i) {
        int c = t + i * 256;
        int rr = c >> 3, cc = c & 7;
        size_t eo = soff + (size_t)e * es + (size_t)(r0 + rr) * sld + c0 + cc * 8;
        floatx4 a = *(const floatx4*)(src + eo);
        floatx4 b = *(const floatx4*)(src + eo + 4);
        bf16x8 v;
#pragma unroll
        for (int j = 0; j < 4; ++j) { v[j] = (bf16)a[j]; v[4 + j] = (bf16)b[j]; }
        // store chunk cc of row rr at swizzled position p = cc ^ ((rr>>3)&7)
        *(bf16x8*)&tile[rr * 64 + ((cc ^ ((rr >> 3) & 7)) * 8)] = v;
    }
    __syncthreads();
#pragma unroll
    for (int i = 0; i < 2; ++i) {
        int c = t + i * 256;
        int oc = c >> 3;       // output row (a source column), 0..63
        int occ = c & 7;       // 16B chunk along r; 8 lanes -> 128B contiguous
        bf16x8 v;
#pragma unroll
        for (int j = 0; j < 8; ++j) {
            int r = occ * 8 + j;
            int p = (oc >> 3) ^ ((r >> 3) & 7);
            v[j] = tile[r * 64 + p * 8 + (oc & 7)];
        }
        *(bf16x8*)&d[(size_t)(c0 + oc) * R + r0 + occ * 8] = v;
    }
}

// ---------------- GEMM1: h[:, chunk] = gelu(gather(xb) @ w1[e][:, chunk] + b1[e][chunk]) ------
// w1t: per-expert [Nc][DIM] bf16 (k=DIM contiguous). hbuf: [NROW][Nc] bf16. b1 fp32.
// v5: 2-buffer (32 KB LDS -> 5 blocks/CU), one barrier/step:
//     {vmcnt(0) own stage(i); barrier; stage(i+1)->buf^1; ds_read(cur); MFMA}
__global__ __launch_bounds__(256) void gemm1_k(
    const bf16* __restrict__ xb, const bf16* __restrict__ w1t, const float* __restrict__ b1,
    const int* __restrict__ counts, const int* __restrict__ base,
    const int* __restrict__ row_token, bf16* __restrict__ hbuf, int Nc, int bias_off)
{
    const int e = blockIdx.z;
    const int cnt = counts[e];
    const int rt = blockIdx.y;
    if (rt * 128 >= cnt) return;
    const int rb = base[e] + rt * 128;
    const int rend = base[e] + cnt;
    const int n0 = blockIdx.x * 128;

    __shared__ __align__(16) bf16 As[2][128 * 32];   // 2 x 8 KB
    __shared__ __align__(16) bf16 Bs[2][128 * 32];   // 2 x 8 KB

    const int t = threadIdx.x;
    const int wv = t >> 6, lane = t & 63;
    // staging slots: slot s covers LDS 16B-chunk s = (row s>>2, pos s&3);
    // pos (s&3) holds data-chunk c = (s&3) ^ ((s>>3)&3)  [= (s&3) ^ ((row>>1)&3)]
    const int s0 = t, s1 = t + 256;
    const int ar0 = s0 >> 2, ac0 = (s0 & 3) ^ ((s0 >> 3) & 3);
    const int ar1 = s1 >> 2, ac1 = (s1 & 3) ^ ((s1 >> 3) & 3);
    int rr0 = rb + ar0; if (rr0 > NROW - 1) rr0 = NROW - 1;   // clamp: padded rows read valid data
    int rr1 = rb + ar1; if (rr1 > NROW - 1) rr1 = NROW - 1;
    const bf16* ga0 = xb + (size_t)row_token[rr0] * DIM + ac0 * 8;
    const bf16* ga1 = xb + (size_t)row_token[rr1] * DIM + ac1 * 8;
    const bf16* wb = w1t + (size_t)e * Nc * DIM;
    const bf16* gb0 = wb + (size_t)(n0 + ar0) * DIM + ac0 * 8;
    const bf16* gb1 = wb + (size_t)(n0 + ar1) * DIM + ac1 * 8;
    const int off0 = wv * 512, off1 = 2048 + wv * 512;   // wave-uniform LDS bases

    floatx4 acc[4][4];
#pragma unroll
    for (int i = 0; i < 4; ++i)
#pragma unroll
        for (int j = 0; j < 4; ++j) acc[i][j] = floatx4{0.f, 0.f, 0.f, 0.f};

    const int wr = (wv >> 1) * 64, wc = (wv & 1) * 64;
    const int lr = lane & 15;
    const int ck = lane >> 4;   // k-chunk 0..3

    // prologue: stage step 0 into buffer 0
    gl_lds16(ga0, &As[0][off0]); gl_lds16(ga1, &As[0][off1]);
    gl_lds16(gb0, &Bs[0][off0]); gl_lds16(gb1, &Bs[0][off1]);

    const int NSTEP = DIM / 32;   // 32
    for (int i = 0; i < NSTEP; ++i) {
        const int bc = i & 1;
        asm volatile("s_waitcnt vmcnt(0)" ::: "memory");   // own stage(i) landed (issued 1 step ago)
        __builtin_amdgcn_s_barrier();                      // all waves: stage(i) visible; buf^1 free
        asm volatile("" ::: "memory");
        if (i + 1 < NSTEP) {                               // stage(i+1) into the other buffer
            const int kn = (i + 1) * 32;
            gl_lds16(ga0 + kn, &As[bc ^ 1][off0]); gl_lds16(ga1 + kn, &As[bc ^ 1][off1]);
            gl_lds16(gb0 + kn, &Bs[bc ^ 1][off0]); gl_lds16(gb1 + kn, &Bs[bc ^ 1][off1]);
        }
        bf16x8 af[4], bg[4];
#pragma unroll
        for (int q = 0; q < 4; ++q) {
            int r = wr + q * 16 + lr;
            af[q] = *(const bf16x8*)&As[bc][r * 32 + ((ck ^ ((r >> 1) & 3)) * 8)];
        }
#pragma unroll
        for (int q = 0; q < 4; ++q) {
            int r = wc + q * 16 + lr;
            bg[q] = *(const bf16x8*)&Bs[bc][r * 32 + ((ck ^ ((r >> 1) & 3)) * 8)];
        }
        __builtin_amdgcn_s_setprio(1);
#pragma unroll
        for (int mi = 0; mi < 4; ++mi)
#pragma unroll
            for (int ni = 0; ni < 4; ++ni)
                acc[mi][ni] = __builtin_amdgcn_mfma_f32_16x16x32_bf16(af[mi], bg[ni], acc[mi][ni], 0, 0, 0);
        __builtin_amdgcn_s_setprio(0);
    }

#pragma unroll
    for (int mi = 0; mi < 4; ++mi) {
#pragma unroll
        for (int r = 0; r < 4; ++r) {
            int m = wr + mi * 16 + (lane >> 4) * 4 + r;  // C/D: row=(lane>>4)*4+reg, col=lane&15
            int gr = rb + m;
            if (gr < rend) {
#pragma unroll
                for (int ni = 0; ni < 4; ++ni) {
                    int col = n0 + wc + ni * 16 + lr;
                    float v = acc[mi][ni][r] + b1[e * HID + bias_off + col];
                    v = 0.5f * v * (1.f + erff(v * 0.70710678f));  // exact GELU
                    hbuf[(size_t)gr * Nc + col] = (bf16)v;
                }
            }
        }
    }
}

// ---------------- GEMM2 (split-K=2, non-atomic): y_ks += h[:, kslice] @ w2[e][kslice, :] -----
// w2t: per-expert [DIM][Kc] bf16 (k=Kc contiguous). hbuf: [NROW][Kc] bf16.
// ybuf: [KSPLIT][NROW][DIM] fp32. grid: (DIM/128, 32, NEXP*KSPLIT).
// bias+gate applied in combine_k. first = (ch==0): write vs accumulate across H-chunks.
__global__ __launch_bounds__(256) void gemm2_k(
    const bf16* __restrict__ hbuf, const bf16* __restrict__ w2t,
    const int* __restrict__ counts, const int* __restrict__ base,
    float* __restrict__ ybuf, int Kc, int first)
{
    const int e  = blockIdx.z >> 1;          // KSPLIT == 2
    const int ks = blockIdx.z & 1;
    const int cnt = counts[e];
    const int rt = blockIdx.y;
    if (rt * 128 >= cnt) return;
    const int rb = base[e] + rt * 128;
    const int rend = base[e] + cnt;
    const int n0 = blockIdx.x * 128;
    const int klen = Kc / KSPLIT;            // multiple of 32
    const int kbeg = ks * klen;

    __shared__ __align__(16) bf16 As[2][128 * 32];
    __shared__ __align__(16) bf16 Bs[2][128 * 32];

    const int t = threadIdx.x;
    const int wv = t >> 6, lane = t & 63;
    const int s0 = t, s1 = t + 256;
    const int ar0 = s0 >> 2, ac0 = (s0 & 3) ^ ((s0 >> 3) & 3);
    const int ar1 = s1 >> 2, ac1 = (s1 & 3) ^ ((s1 >> 3) & 3);
    int rr0 = rb + ar0; if (rr0 > NROW - 1) rr0 = NROW - 1;
    int rr1 = rb + ar1; if (rr1 > NROW - 1) rr1 = NROW - 1;
    const bf16* ga0 = hbuf + (size_t)rr0 * Kc + kbeg + ac0 * 8;
    const bf16* ga1 = hbuf + (size_t)rr1 * Kc + kbeg + ac1 * 8;
    const bf16* wb = w2t + (size_t)e * DIM * Kc;
    const bf16* gb0 = wb + (size_t)(n0 + ar0) * Kc + kbeg + ac0 * 8;
    const bf16* gb1 = wb + (size_t)(n0 + ar1) * Kc + kbeg + ac1 * 8;
    const int off0 = wv * 512, off1 = 2048 + wv * 512;

    floatx4 acc[4][4];
#pragma unroll
    for (int i = 0; i < 4; ++i)
#pragma unroll
        for (int j = 0; j < 4; ++j) acc[i][j] = floatx4{0.f, 0.f, 0.f, 0.f};

    const int wr = (wv >> 1) * 64, wc = (wv & 1) * 64;
    const int lr = lane & 15;
    const int ck = lane >> 4;

    gl_lds16(ga0, &As[0][off0]); gl_lds16(ga1, &As[0][off1]);
    gl_lds16(gb0, &Bs[0][off0]); gl_lds16(gb1, &Bs[0][off1]);

    const int nstep = klen >> 5;
    for (int i = 0; i < nstep; ++i) {
        const int bc = i & 1;
        asm volatile("s_waitcnt vmcnt(0)" ::: "memory");
        __builtin_amdgcn_s_barrier();
        asm volatile("" ::: "memory");
        if (i + 1 < nstep) {
            const int kn = (i + 1) * 32;
            gl_lds16(ga0 + kn, &As[bc ^ 1][off0]); gl_lds16(ga1 + kn, &As[bc ^ 1][off1]);
            gl_lds16(gb0 + kn, &Bs[bc ^ 1][off0]); gl_lds16(gb1 + kn, &Bs[bc ^ 1][off1]);
        }
        bf16x8 af[4], bg[4];
#pragma unroll
        for (int q = 0; q < 4; ++q) {
            int r = wr + q * 16 + lr;
            af[q] = *(const bf16x8*)&As[bc][r * 32 + ((ck ^ ((r >> 1) & 3)) * 8)];
        }
#pragma unroll
        for (int q = 0; q < 4; ++q) {
            int r = wc + q * 16 + lr;
            bg[q] = *(const bf16x8*)&Bs[bc][r * 32 + ((ck ^ ((r >> 1) & 3)) * 8)];
        }
        __builtin_amdgcn_s_setprio(1);
#pragma unroll
        for (int mi = 0; mi < 4; ++mi)
#pragma unroll
            for (int ni = 0; ni < 4; ++ni)
                acc[mi][ni] = __builtin_amdgcn_mfma_f32_16x16x32_bf16(af[mi], bg[ni], acc[mi][ni], 0, 0, 0);
        __builtin_amdgcn_s_setprio(0);
    }

    float* yb = ybuf + (size_t)ks * NROW * DIM;
#pragma unroll
    for (int mi = 0; mi < 4; ++mi) {
#pragma unroll
        for (int r = 0; r < 4; ++r) {
            int m = wr + mi * 16 + (lane >> 4) * 4 + r;
            int gr = rb + m;
            if (gr < rend) {
#pragma unroll
                for (int ni = 0; ni < 4; ++ni) {
                    int col = n0 + wc + ni * 16 + lr;
                    size_t idx = (size_t)gr * DIM + col;
                    float v = acc[mi][ni][r];
                    yb[idx] = first ? v : (yb[idx] + v);
                }
            }
        }
    }
}

// ---------------- combine: out[t] = Σ_k g_k * (y0[row_k] + y1[row_k] + b2[e_k]) --------------
__global__ __launch_bounds__(256) void combine_k(
    const float* __restrict__ ybuf, const int* __restrict__ tok_row,
    const int* __restrict__ tok_e, const float* __restrict__ tok_g,
    const float* __restrict__ b2, float* __restrict__ out)
{
    int i = blockIdx.x * 256 + threadIdx.x;
    int tk = i >> 8;            // DIM/4 == 256 chunks per token
    int dc = (i & 255) * 4;
    int ra = tok_row[tk * 2], rbx = tok_row[tk * 2 + 1];
    int ea = tok_e[tk * 2],  eb = tok_e[tk * 2 + 1];
    float ga = tok_g[tk * 2], gbv = tok_g[tk * 2 + 1];
    const float* y0 = ybuf;
    const float* y1 = ybuf + (size_t)NROW * DIM;
    floatx4 a0 = *(const floatx4*)&y0[(size_t)ra * DIM + dc];
    floatx4 a1 = *(const floatx4*)&y1[(size_t)ra * DIM + dc];
    floatx4 b0 = *(const floatx4*)&y0[(size_t)rbx * DIM + dc];
    floatx4 b1v = *(const floatx4*)&y1[(size_t)rbx * DIM + dc];
    floatx4 b2a = *(const floatx4*)&b2[ea * DIM + dc];
    floatx4 b2b = *(const floatx4*)&b2[eb * DIM + dc];
    floatx4 o;
#pragma unroll
    for (int j = 0; j < 4; ++j)
        o[j] = ga * (a0[j] + a1[j] + b2a[j]) + gbv * (b0[j] + b1v[j] + b2b[j]);
    *(floatx4*)&out[(size_t)tk * DIM + dc] = o;
}

extern "C" void kernel_launch(void* const* d_in, const int* in_sizes, int n_in,
                              void* d_out, int out_size, void* d_ws, size_t ws_size,
                              hipStream_t stream)
{
    const float* x  = (const float*)d_in[0];
    const float* gw = (const float*)d_in[1];
    const float* gb = (const float*)d_in[2];
    const float* w1 = (const float*)d_in[3];
    const float* b1 = (const float*)d_in[4];
    const float* w2 = (const float*)d_in[5];
    const float* b2 = (const float*)d_in[6];
    float* out = (float*)d_out;

    char* w = (char*)d_ws;
    int*   counts  = (int*)(w + 0);        // 8 ints
    int*   counts2 = (int*)(w + 32);       // 8 ints
    int*   base    = (int*)(w + 64);       // 9 ints
    int*   tok_e   = (int*)(w + 256);
    float* tok_g   = (float*)(w + 256 + 32768);
    int*   row_tok = (int*)(w + 256 + 2 * 32768);
    float* row_g   = (float*)(w + 256 + 3 * 32768);
    int*   tok_row = (int*)(w + 256 + 4 * 32768);
    size_t off = 256 + 5 * 32768;                                       // 256-aligned
    bf16*  xb   = (bf16*)(w + off);   off += (size_t)NTOK * DIM * 2;    // 8 MiB
    float* ybuf = (float*)(w + off);  off += (size_t)KSPLIT * NROW * DIM * 4;  // 64 MiB

    // choose H-chunk so total footprint fits ws_size (deterministic across calls)
    int Hc = HID;
    for (;;) {
        size_t need = off + (size_t)NEXP * Hc * DIM * 2 + (size_t)NROW * Hc * 2;
        if (need <= ws_size || Hc == 128) break;
        Hc >>= 1;
    }
    bf16* wT   = (bf16*)(w + off);  off += (size_t)NEXP * Hc * DIM * 2;  // per chunk: w1^T slice, then w2^T slice
    bf16* hbuf = (bf16*)(w + off);                                       // [NROW][Hc]

    zero_k<<<1, 64, 0, stream>>>(counts);
    router_k<<<NTOK / 4, 256, 0, stream>>>(x, gw, gb, counts, tok_e, tok_g);
    scan_k<<<1, 64, 0, stream>>>(counts, base);
    scatter_k<<<NTOK / 256, 256, 0, stream>>>(tok_e, tok_g, base, counts2, row_tok, row_g, tok_row);
    convx_k<<<(NTOK * DIM) / 2048, 256, 0, stream>>>(x, xb);

    const int nc = HID / Hc;
    for (int ch = 0; ch < nc; ++ch) {
        // w1[e] cols [ch*Hc, +Hc): logical [DIM][Hc] row-stride HID -> wT [Hc][DIM]
        transpose_k<<<dim3(Hc / 64, DIM / 64, NEXP), 256, 0, stream>>>(
            w1, wT, DIM, HID, (size_t)ch * Hc, (size_t)DIM * HID, (size_t)Hc * DIM);
        gemm1_k<<<dim3(Hc / 128, 32, NEXP), 256, 0, stream>>>(
            xb, wT, b1, counts, base, row_tok, hbuf, Hc, ch * Hc);
        // w2[e] rows [ch*Hc, +Hc): logical [Hc][DIM] contiguous -> wT [DIM][Hc]
        transpose_k<<<dim3(DIM / 64, Hc / 64, NEXP), 256, 0, stream>>>(
            w2, wT, Hc, DIM, (size_t)ch * Hc * DIM, (size_t)HID * DIM, (size_t)DIM * Hc);
        gemm2_k<<<dim3(DIM / 128, 32, NEXP * KSPLIT), 256, 0, stream>>>(
            hbuf, wT, counts, base, ybuf, Hc, ch == 0);
    }

    combine_k<<<NTOK, 256, 0, stream>>>(ybuf, tok_row, tok_e, tok_g, b2, out);
}

// Round 5
// 697.534 us; speedup vs baseline: 1.0967x; 1.0367x over previous
//
#include <hip/hip_runtime.h>
#include <math.h>

#define NTOK 4096   // B*T tokens
#define DIM  1024
#define HID  4096
#define NEXP 8
#define NROW 8192   // NTOK * K (top-2): every token occupies exactly 2 rows
#define KSPLIT 2    // non-atomic split-K for gemm2: separate ybuf slices, summed in combine

typedef __bf16 bf16;
typedef __attribute__((ext_vector_type(8))) __bf16 bf16x8;
typedef __attribute__((ext_vector_type(4))) float floatx4;

// async global->LDS, 16B per lane. LDS dest is wave-uniform base + lane*16.
__device__ __forceinline__ void gl_lds16(const bf16* g, bf16* l) {
    __builtin_amdgcn_global_load_lds(
        (const __attribute__((address_space(1))) void*)g,
        (__attribute__((address_space(3))) void*)l, 16, 0, 0);
}

// branchless GELU: 0.5v(1+erf(v/sqrt2)), erf via A&S 7.1.26 (|eps|<=1.5e-7 abs).
// ~15 full-rate VALU ops vs ~40 for libm erff. Error << bf16 quantization of h.
__device__ __forceinline__ float gelu_f(float v) {
    float x  = v * 0.70710678118654752f;
    float ax = fabsf(x);
    float t  = __builtin_amdgcn_rcpf(fmaf(0.3275911f, ax, 1.0f));
    float p  = fmaf(fmaf(fmaf(fmaf(1.061405429f, t, -1.453152027f),
                              t, 1.421413741f),
                         t, -0.284496736f),
                    t, 0.254829592f);
    p *= t;
    float ex = __expf(-x * x);          // v_exp_f32 path
    float er = fmaf(-p, ex, 1.0f);      // erf(|x|)
    er = copysignf(er, v);
    return 0.5f * v * (1.0f + er);
}

__global__ void zero_k(int* __restrict__ p) {
    if (threadIdx.x < 16) p[threadIdx.x] = 0;   // counts[8] + counts2[8]
}

// ---- convert x (fp32) -> bf16 xb for the MFMA path
__global__ __launch_bounds__(256) void convx_k(const float* __restrict__ x,
                                               bf16* __restrict__ xb)
{
    size_t gid = (size_t)blockIdx.x * 256 + threadIdx.x;
    size_t eo = gid * 8;
    floatx4 a = *(const floatx4*)(x + eo);
    floatx4 b = *(const floatx4*)(x + eo + 4);
    bf16x8 v;
#pragma unroll
    for (int j = 0; j < 4; ++j) { v[j] = (bf16)a[j]; v[4 + j] = (bf16)b[j]; }
    *(bf16x8*)&xb[eo] = v;
}

// ---------------- router: one wave per token, FULL FP32 (top-k must match np ref exactly) ----
// v2: gws stored transposed [NEXP][DIM]; lane d-slice strided by 64 -> conflict-free LDS reads
//     (old layout had lane-stride 128 words = all 64 lanes on one bank, 64-way conflict)
//     and perfectly coalesced x loads (lane-consecutive floats).
__global__ __launch_bounds__(256) void router_k(
    const float* __restrict__ x, const float* __restrict__ gw, const float* __restrict__ gb,
    int* __restrict__ counts, int* __restrict__ tok_e, float* __restrict__ tok_g)
{
    __shared__ float gws[NEXP][DIM];   // 32 KB fp32, transposed
    int t = threadIdx.x;
#pragma unroll
    for (int i = 0; i < 32; ++i) {
        int g = i * 256 + t;                 // coalesced read of gw [DIM][NEXP]
        gws[g & 7][g >> 3] = gw[g];
    }
    __syncthreads();

    int gid = blockIdx.x * 256 + t;
    int wv = gid >> 6, lane = gid & 63;       // grid covers exactly NTOK waves
    const float* xr = x + (size_t)wv * DIM;
    float acc[NEXP];
#pragma unroll
    for (int e = 0; e < NEXP; ++e) acc[e] = 0.f;
#pragma unroll
    for (int j = 0; j < 16; ++j) {
        int d = lane + j * 64;               // lane-consecutive: coalesced + bank-conflict-free
        float xv = xr[d];
#pragma unroll
        for (int e = 0; e < NEXP; ++e) acc[e] += xv * gws[e][d];
    }
#pragma unroll
    for (int off = 32; off > 0; off >>= 1) {
#pragma unroll
        for (int e = 0; e < NEXP; ++e) acc[e] += __shfl_xor(acc[e], off, 64);
    }
    if (lane == 0) {
        float lg[NEXP], m = -1e30f;
        for (int e = 0; e < NEXP; ++e) { lg[e] = acc[e] + gb[e]; m = fmaxf(m, lg[e]); }
        float p[NEXP], s = 0.f;
        for (int e = 0; e < NEXP; ++e) { p[e] = expf(lg[e] - m); s += p[e]; }
        int e0 = 0;
        for (int e = 1; e < NEXP; ++e) if (p[e] > p[e0]) e0 = e;  // strict > : first index wins ties
        int e1 = (e0 == 0) ? 1 : 0;
        for (int e = 0; e < NEXP; ++e) if (e != e0 && p[e] > p[e1]) e1 = e;
        float g0 = p[e0] / s, g1 = p[e1] / s;
        float gs = g0 + g1 + 1e-9f;
        g0 /= gs; g1 /= gs;
        tok_e[wv * 2] = e0; tok_e[wv * 2 + 1] = e1;
        tok_g[wv * 2] = g0; tok_g[wv * 2 + 1] = g1;
        atomicAdd(&counts[e0], 1);
        atomicAdd(&counts[e1], 1);
    }
}

__global__ void scan_k(const int* __restrict__ counts, int* __restrict__ base)
{
    if (threadIdx.x == 0) {
        int s = 0;
#pragma unroll
        for (int e = 0; e < NEXP; ++e) { base[e] = s; s += counts[e]; }
        base[NEXP] = s;
    }
}

__global__ __launch_bounds__(256) void scatter_k(
    const int* __restrict__ tok_e, const float* __restrict__ tok_g,
    const int* __restrict__ base, int* __restrict__ counts2,
    int* __restrict__ row_token, float* __restrict__ row_gate, int* __restrict__ tok_row)
{
    int tk = blockIdx.x * 256 + threadIdx.x;
    if (tk >= NTOK) return;
#pragma unroll
    for (int k = 0; k < 2; ++k) {
        int e = tok_e[tk * 2 + k];
        int slot = atomicAdd(&counts2[e], 1);
        int r = base[e] + slot;
        row_token[r] = tk;
        row_gate[r] = tok_g[tk * 2 + k];
        tok_row[tk * 2 + k] = r;
    }
}

// ---- batched tile transpose + fp32->bf16 conversion:
// logical src M[r][c] (r<R, row stride sld, element offset soff) -> dst bf16 [c][r] (ld=R)
// per-expert strides es (src), ed (dst). grid: (C/64, R/64, NEXP)
// XOR-swizzled tile: phase-2 gathers along r and writes 128B-contiguous segments.
__global__ __launch_bounds__(256) void transpose_k(
    const float* __restrict__ src, bf16* __restrict__ dst,
    int R, int sld, size_t soff, size_t es, size_t ed)
{
    int e = blockIdx.z;
    bf16* d = dst + (size_t)e * ed;
    __shared__ __align__(16) bf16 tile[64 * 64];
    int t = threadIdx.x;
    int r0 = blockIdx.y * 64, c0 = blockIdx.x * 64;
#pragma unroll
    for (int i = 0; i < 2; ++i) {
        int c = t + i * 256;
        int rr = c >> 3, cc = c & 7;
        size_t eo = soff + (size_t)e * es + (size_t)(r0 + rr) * sld + c0 + cc * 8;
        floatx4 a = *(const floatx4*)(src + eo);
        floatx4 b = *(const floatx4*)(src + eo + 4);
        bf16x8 v;
#pragma unroll
        for (int j = 0; j < 4; ++j) { v[j] = (bf16)a[j]; v[4 + j] = (bf16)b[j]; }
        // store chunk cc of row rr at swizzled position p = cc ^ ((rr>>3)&7)
        *(bf16x8*)&tile[rr * 64 + ((cc ^ ((rr >> 3) & 7)) * 8)] = v;
    }
    __syncthreads();
#pragma unroll
    for (int i = 0; i < 2; ++i) {
        int c = t + i * 256;
        int oc = c >> 3;       // output row (a source column), 0..63
        int occ = c & 7;       // 16B chunk along r; 8 lanes -> 128B contiguous
        bf16x8 v;
#pragma unroll
        for (int j = 0; j < 8; ++j) {
            int r = occ * 8 + j;
            int p = (oc >> 3) ^ ((r >> 3) & 7);
            v[j] = tile[r * 64 + p * 8 + (oc & 7)];
        }
        *(bf16x8*)&d[(size_t)(c0 + oc) * R + r0 + occ * 8] = v;
    }
}

// ---------------- GEMM1: h[:, chunk] = gelu(gather(xb) @ w1[e][:, chunk] + b1[e][chunk]) ------
// w1t: per-expert [Nc][DIM] bf16 (k=DIM contiguous). hbuf: [NROW][Nc] bf16. b1 fp32.
// v6: 2-buffer pipeline + fast branchless GELU epilogue (was libm erff: ~half the kernel's VALU).
__global__ __launch_bounds__(256) void gemm1_k(
    const bf16* __restrict__ xb, const bf16* __restrict__ w1t, const float* __restrict__ b1,
    const int* __restrict__ counts, const int* __restrict__ base,
    const int* __restrict__ row_token, bf16* __restrict__ hbuf, int Nc, int bias_off)
{
    const int e = blockIdx.z;
    const int cnt = counts[e];
    const int rt = blockIdx.y;
    if (rt * 128 >= cnt) return;
    const int rb = base[e] + rt * 128;
    const int rend = base[e] + cnt;
    const int n0 = blockIdx.x * 128;

    __shared__ __align__(16) bf16 As[2][128 * 32];   // 2 x 8 KB
    __shared__ __align__(16) bf16 Bs[2][128 * 32];   // 2 x 8 KB

    const int t = threadIdx.x;
    const int wv = t >> 6, lane = t & 63;
    // staging slots: slot s covers LDS 16B-chunk s = (row s>>2, pos s&3);
    // pos (s&3) holds data-chunk c = (s&3) ^ ((s>>3)&3)  [= (s&3) ^ ((row>>1)&3)]
    const int s0 = t, s1 = t + 256;
    const int ar0 = s0 >> 2, ac0 = (s0 & 3) ^ ((s0 >> 3) & 3);
    const int ar1 = s1 >> 2, ac1 = (s1 & 3) ^ ((s1 >> 3) & 3);
    int rr0 = rb + ar0; if (rr0 > NROW - 1) rr0 = NROW - 1;   // clamp: padded rows read valid data
    int rr1 = rb + ar1; if (rr1 > NROW - 1) rr1 = NROW - 1;
    const bf16* ga0 = xb + (size_t)row_token[rr0] * DIM + ac0 * 8;
    const bf16* ga1 = xb + (size_t)row_token[rr1] * DIM + ac1 * 8;
    const bf16* wb = w1t + (size_t)e * Nc * DIM;
    const bf16* gb0 = wb + (size_t)(n0 + ar0) * DIM + ac0 * 8;
    const bf16* gb1 = wb + (size_t)(n0 + ar1) * DIM + ac1 * 8;
    const int off0 = wv * 512, off1 = 2048 + wv * 512;   // wave-uniform LDS bases

    floatx4 acc[4][4];
#pragma unroll
    for (int i = 0; i < 4; ++i)
#pragma unroll
        for (int j = 0; j < 4; ++j) acc[i][j] = floatx4{0.f, 0.f, 0.f, 0.f};

    const int wr = (wv >> 1) * 64, wc = (wv & 1) * 64;
    const int lr = lane & 15;
    const int ck = lane >> 4;   // k-chunk 0..3

    // prologue: stage step 0 into buffer 0
    gl_lds16(ga0, &As[0][off0]); gl_lds16(ga1, &As[0][off1]);
    gl_lds16(gb0, &Bs[0][off0]); gl_lds16(gb1, &Bs[0][off1]);

    const int NSTEP = DIM / 32;   // 32
#pragma unroll 2
    for (int i = 0; i < NSTEP; ++i) {
        const int bc = i & 1;
        asm volatile("s_waitcnt vmcnt(0)" ::: "memory");   // own stage(i) landed (issued 1 step ago)
        __builtin_amdgcn_s_barrier();                      // all waves: stage(i) visible; buf^1 free
        asm volatile("" ::: "memory");
        if (i + 1 < NSTEP) {                               // stage(i+1) into the other buffer
            const int kn = (i + 1) * 32;
            gl_lds16(ga0 + kn, &As[bc ^ 1][off0]); gl_lds16(ga1 + kn, &As[bc ^ 1][off1]);
            gl_lds16(gb0 + kn, &Bs[bc ^ 1][off0]); gl_lds16(gb1 + kn, &Bs[bc ^ 1][off1]);
        }
        bf16x8 af[4], bg[4];
#pragma unroll
        for (int q = 0; q < 4; ++q) {
            int r = wr + q * 16 + lr;
            af[q] = *(const bf16x8*)&As[bc][r * 32 + ((ck ^ ((r >> 1) & 3)) * 8)];
        }
#pragma unroll
        for (int q = 0; q < 4; ++q) {
            int r = wc + q * 16 + lr;
            bg[q] = *(const bf16x8*)&Bs[bc][r * 32 + ((ck ^ ((r >> 1) & 3)) * 8)];
        }
        __builtin_amdgcn_s_setprio(1);
#pragma unroll
        for (int mi = 0; mi < 4; ++mi)
#pragma unroll
            for (int ni = 0; ni < 4; ++ni)
                acc[mi][ni] = __builtin_amdgcn_mfma_f32_16x16x32_bf16(af[mi], bg[ni], acc[mi][ni], 0, 0, 0);
        __builtin_amdgcn_s_setprio(0);
    }

#pragma unroll
    for (int mi = 0; mi < 4; ++mi) {
#pragma unroll
        for (int r = 0; r < 4; ++r) {
            int m = wr + mi * 16 + (lane >> 4) * 4 + r;  // C/D: row=(lane>>4)*4+reg, col=lane&15
            int gr = rb + m;
            if (gr < rend) {
#pragma unroll
                for (int ni = 0; ni < 4; ++ni) {
                    int col = n0 + wc + ni * 16 + lr;
                    float v = acc[mi][ni][r] + b1[e * HID + bias_off + col];
                    hbuf[(size_t)gr * Nc + col] = (bf16)gelu_f(v);
                }
            }
        }
    }
}

// ---------------- GEMM2 (split-K=2, non-atomic): y_ks += h[:, kslice] @ w2[e][kslice, :] -----
// w2t: per-expert [DIM][Kc] bf16 (k=Kc contiguous). hbuf: [NROW][Kc] bf16.
// ybuf: [KSPLIT][NROW][DIM] fp32. grid: (DIM/128, 32, NEXP*KSPLIT).
// bias+gate applied in combine_k. first = (ch==0): write vs accumulate across H-chunks.
__global__ __launch_bounds__(256) void gemm2_k(
    const bf16* __restrict__ hbuf, const bf16* __restrict__ w2t,
    const int* __restrict__ counts, const int* __restrict__ base,
    float* __restrict__ ybuf, int Kc, int first)
{
    const int e  = blockIdx.z >> 1;          // KSPLIT == 2
    const int ks = blockIdx.z & 1;
    const int cnt = counts[e];
    const int rt = blockIdx.y;
    if (rt * 128 >= cnt) return;
    const int rb = base[e] + rt * 128;
    const int rend = base[e] + cnt;
    const int n0 = blockIdx.x * 128;
    const int klen = Kc / KSPLIT;            // multiple of 32
    const int kbeg = ks * klen;

    __shared__ __align__(16) bf16 As[2][128 * 32];
    __shared__ __align__(16) bf16 Bs[2][128 * 32];

    const int t = threadIdx.x;
    const int wv = t >> 6, lane = t & 63;
    const int s0 = t, s1 = t + 256;
    const int ar0 = s0 >> 2, ac0 = (s0 & 3) ^ ((s0 >> 3) & 3);
    const int ar1 = s1 >> 2, ac1 = (s1 & 3) ^ ((s1 >> 3) & 3);
    int rr0 = rb + ar0; if (rr0 > NROW - 1) rr0 = NROW - 1;
    int rr1 = rb + ar1; if (rr1 > NROW - 1) rr1 = NROW - 1;
    const bf16* ga0 = hbuf + (size_t)rr0 * Kc + kbeg + ac0 * 8;
    const bf16* ga1 = hbuf + (size_t)rr1 * Kc + kbeg + ac1 * 8;
    const bf16* wb = w2t + (size_t)e * DIM * Kc;
    const bf16* gb0 = wb + (size_t)(n0 + ar0) * Kc + kbeg + ac0 * 8;
    const bf16* gb1 = wb + (size_t)(n0 + ar1) * Kc + kbeg + ac1 * 8;
    const int off0 = wv * 512, off1 = 2048 + wv * 512;

    floatx4 acc[4][4];
#pragma unroll
    for (int i = 0; i < 4; ++i)
#pragma unroll
        for (int j = 0; j < 4; ++j) acc[i][j] = floatx4{0.f, 0.f, 0.f, 0.f};

    const int wr = (wv >> 1) * 64, wc = (wv & 1) * 64;
    const int lr = lane & 15;
    const int ck = lane >> 4;

    gl_lds16(ga0, &As[0][off0]); gl_lds16(ga1, &As[0][off1]);
    gl_lds16(gb0, &Bs[0][off0]); gl_lds16(gb1, &Bs[0][off1]);

    const int nstep = klen >> 5;
#pragma unroll 2
    for (int i = 0; i < nstep; ++i) {
        const int bc = i & 1;
        asm volatile("s_waitcnt vmcnt(0)" ::: "memory");
        __builtin_amdgcn_s_barrier();
        asm volatile("" ::: "memory");
        if (i + 1 < nstep) {
            const int kn = (i + 1) * 32;
            gl_lds16(ga0 + kn, &As[bc ^ 1][off0]); gl_lds16(ga1 + kn, &As[bc ^ 1][off1]);
            gl_lds16(gb0 + kn, &Bs[bc ^ 1][off0]); gl_lds16(gb1 + kn, &Bs[bc ^ 1][off1]);
        }
        bf16x8 af[4], bg[4];
#pragma unroll
        for (int q = 0; q < 4; ++q) {
            int r = wr + q * 16 + lr;
            af[q] = *(const bf16x8*)&As[bc][r * 32 + ((ck ^ ((r >> 1) & 3)) * 8)];
        }
#pragma unroll
        for (int q = 0; q < 4; ++q) {
            int r = wc + q * 16 + lr;
            bg[q] = *(const bf16x8*)&Bs[bc][r * 32 + ((ck ^ ((r >> 1) & 3)) * 8)];
        }
        __builtin_amdgcn_s_setprio(1);
#pragma unroll
        for (int mi = 0; mi < 4; ++mi)
#pragma unroll
            for (int ni = 0; ni < 4; ++ni)
                acc[mi][ni] = __builtin_amdgcn_mfma_f32_16x16x32_bf16(af[mi], bg[ni], acc[mi][ni], 0, 0, 0);
        __builtin_amdgcn_s_setprio(0);
    }

    float* yb = ybuf + (size_t)ks * NROW * DIM;
#pragma unroll
    for (int mi = 0; mi < 4; ++mi) {
#pragma unroll
        for (int r = 0; r < 4; ++r) {
            int m = wr + mi * 16 + (lane >> 4) * 4 + r;
            int gr = rb + m;
            if (gr < rend) {
#pragma unroll
                for (int ni = 0; ni < 4; ++ni) {
                    int col = n0 + wc + ni * 16 + lr;
                    size_t idx = (size_t)gr * DIM + col;
                    float v = acc[mi][ni][r];
                    yb[idx] = first ? v : (yb[idx] + v);
                }
            }
        }
    }
}

// ---------------- combine: out[t] = Σ_k g_k * (y0[row_k] + y1[row_k] + b2[e_k]) --------------
__global__ __launch_bounds__(256) void combine_k(
    const float* __restrict__ ybuf, const int* __restrict__ tok_row,
    const int* __restrict__ tok_e, const float* __restrict__ tok_g,
    const float* __restrict__ b2, float* __restrict__ out)
{
    int i = blockIdx.x * 256 + threadIdx.x;
    int tk = i >> 8;            // DIM/4 == 256 chunks per token
    int dc = (i & 255) * 4;
    int ra = tok_row[tk * 2], rbx = tok_row[tk * 2 + 1];
    int ea = tok_e[tk * 2],  eb = tok_e[tk * 2 + 1];
    float ga = tok_g[tk * 2], gbv = tok_g[tk * 2 + 1];
    const float* y0 = ybuf;
    const float* y1 = ybuf + (size_t)NROW * DIM;
    floatx4 a0 = *(const floatx4*)&y0[(size_t)ra * DIM + dc];
    floatx4 a1 = *(const floatx4*)&y1[(size_t)ra * DIM + dc];
    floatx4 b0 = *(const floatx4*)&y0[(size_t)rbx * DIM + dc];
    floatx4 b1v = *(const floatx4*)&y1[(size_t)rbx * DIM + dc];
    floatx4 b2a = *(const floatx4*)&b2[ea * DIM + dc];
    floatx4 b2b = *(const floatx4*)&b2[eb * DIM + dc];
    floatx4 o;
#pragma unroll
    for (int j = 0; j < 4; ++j)
        o[j] = ga * (a0[j] + a1[j] + b2a[j]) + gbv * (b0[j] + b1v[j] + b2b[j]);
    *(floatx4*)&out[(size_t)tk * DIM + dc] = o;
}

extern "C" void kernel_launch(void* const* d_in, const int* in_sizes, int n_in,
                              void* d_out, int out_size, void* d_ws, size_t ws_size,
                              hipStream_t stream)
{
    const float* x  = (const float*)d_in[0];
    const float* gw = (const float*)d_in[1];
    const float* gb = (const float*)d_in[2];
    const float* w1 = (const float*)d_in[3];
    const float* b1 = (const float*)d_in[4];
    const float* w2 = (const float*)d_in[5];
    const float* b2 = (const float*)d_in[6];
    float* out = (float*)d_out;

    char* w = (char*)d_ws;
    int*   counts  = (int*)(w + 0);        // 8 ints
    int*   counts2 = (int*)(w + 32);       // 8 ints
    int*   base    = (int*)(w + 64);       // 9 ints
    int*   tok_e   = (int*)(w + 256);
    float* tok_g   = (float*)(w + 256 + 32768);
    int*   row_tok = (int*)(w + 256 + 2 * 32768);
    float* row_g   = (float*)(w + 256 + 3 * 32768);
    int*   tok_row = (int*)(w + 256 + 4 * 32768);
    size_t off = 256 + 5 * 32768;                                       // 256-aligned
    bf16*  xb   = (bf16*)(w + off);   off += (size_t)NTOK * DIM * 2;    // 8 MiB
    float* ybuf = (float*)(w + off);  off += (size_t)KSPLIT * NROW * DIM * 4;  // 64 MiB

    // choose H-chunk so total footprint fits ws_size (deterministic across calls)
    int Hc = HID;
    for (;;) {
        size_t need = off + (size_t)NEXP * Hc * DIM * 2 + (size_t)NROW * Hc * 2;
        if (need <= ws_size || Hc == 128) break;
        Hc >>= 1;
    }
    bf16* wT   = (bf16*)(w + off);  off += (size_t)NEXP * Hc * DIM * 2;  // per chunk: w1^T slice, then w2^T slice
    bf16* hbuf = (bf16*)(w + off);                                       // [NROW][Hc]

    zero_k<<<1, 64, 0, stream>>>(counts);
    router_k<<<NTOK / 4, 256, 0, stream>>>(x, gw, gb, counts, tok_e, tok_g);
    scan_k<<<1, 64, 0, stream>>>(counts, base);
    scatter_k<<<NTOK / 256, 256, 0, stream>>>(tok_e, tok_g, base, counts2, row_tok, row_g, tok_row);
    convx_k<<<(NTOK * DIM) / 2048, 256, 0, stream>>>(x, xb);

    const int nc = HID / Hc;
    for (int ch = 0; ch < nc; ++ch) {
        // w1[e] cols [ch*Hc, +Hc): logical [DIM][Hc] row-stride HID -> wT [Hc][DIM]
        transpose_k<<<dim3(Hc / 64, DIM / 64, NEXP), 256, 0, stream>>>(
            w1, wT, DIM, HID, (size_t)ch * Hc, (size_t)DIM * HID, (size_t)Hc * DIM);
        gemm1_k<<<dim3(Hc / 128, 32, NEXP), 256, 0, stream>>>(
            xb, wT, b1, counts, base, row_tok, hbuf, Hc, ch * Hc);
        // w2[e] rows [ch*Hc, +Hc): logical [Hc][DIM] contiguous -> wT [DIM][Hc]
        transpose_k<<<dim3(DIM / 64, Hc / 64, NEXP), 256, 0, stream>>>(
            w2, wT, Hc, DIM, (size_t)ch * Hc * DIM, (size_t)HID * DIM, (size_t)DIM * Hc);
        gemm2_k<<<dim3(DIM / 128, 32, NEXP * KSPLIT), 256, 0, stream>>>(
            hbuf, wT, counts, base, ybuf, Hc, ch == 0);
    }

    combine_k<<<NTOK, 256, 0, stream>>>(ybuf, tok_row, tok_e, tok_g, b2, out);
}

// Round 6
// 694.244 us; speedup vs baseline: 1.1019x; 1.0047x over previous
//
#include <hip/hip_runtime.h>
#include <math.h>

#define NTOK 4096   // B*T tokens
#define DIM  1024
#define HID  4096
#define NEXP 8
#define NROW 8192   // NTOK * K (top-2): every token occupies exactly 2 rows
#define KSPLIT 2    // non-atomic split-K for gemm2: separate ybuf slices, summed in combine

typedef __bf16 bf16;
typedef __attribute__((ext_vector_type(8))) __bf16 bf16x8;
typedef __attribute__((ext_vector_type(4))) float floatx4;

// async global->LDS, 16B per lane. LDS dest is wave-uniform base + lane*16.
__device__ __forceinline__ void gl_lds16(const bf16* g, bf16* l) {
    __builtin_amdgcn_global_load_lds(
        (const __attribute__((address_space(1))) void*)g,
        (__attribute__((address_space(3))) void*)l, 16, 0, 0);
}

// branchless GELU: 0.5v(1+erf(v/sqrt2)), erf via A&S 7.1.26 (|eps|<=1.5e-7 abs).
// ~15 full-rate VALU ops vs ~40 for libm erff. Error << bf16 quantization of h.
__device__ __forceinline__ float gelu_f(float v) {
    float x  = v * 0.70710678118654752f;
    float ax = fabsf(x);
    float t  = __builtin_amdgcn_rcpf(fmaf(0.3275911f, ax, 1.0f));
    float p  = fmaf(fmaf(fmaf(fmaf(1.061405429f, t, -1.453152027f),
                              t, 1.421413741f),
                         t, -0.284496736f),
                    t, 0.254829592f);
    p *= t;
    float ex = __expf(-x * x);          // v_exp_f32 path
    float er = fmaf(-p, ex, 1.0f);      // erf(|x|)
    er = copysignf(er, v);
    return 0.5f * v * (1.0f + er);
}

__global__ void zero_k(int* __restrict__ p) {
    if (threadIdx.x < 16) p[threadIdx.x] = 0;   // counts[8] + counts2[8]
}

// ---------------- router (+ fused x->bf16 conversion): one wave per token ----------------
// gws transposed [NEXP][DIM]; lane d-slice strided by 64 -> conflict-free LDS reads and
// coalesced x loads. While the row is in registers, also emit xb (bf16) -- removes convx_k's
// separate 16 MiB re-read of x.
__global__ __launch_bounds__(256) void router_k(
    const float* __restrict__ x, const float* __restrict__ gw, const float* __restrict__ gb,
    int* __restrict__ counts, int* __restrict__ tok_e, float* __restrict__ tok_g,
    bf16* __restrict__ xb)
{
    __shared__ float gws[NEXP][DIM];   // 32 KB fp32, transposed
    int t = threadIdx.x;
#pragma unroll
    for (int i = 0; i < 32; ++i) {
        int g = i * 256 + t;                 // coalesced read of gw [DIM][NEXP]
        gws[g & 7][g >> 3] = gw[g];
    }
    __syncthreads();

    int gid = blockIdx.x * 256 + t;
    int wv = gid >> 6, lane = gid & 63;       // grid covers exactly NTOK waves
    const float* xr = x + (size_t)wv * DIM;
    bf16* xw = xb + (size_t)wv * DIM;
    float acc[NEXP];
#pragma unroll
    for (int e = 0; e < NEXP; ++e) acc[e] = 0.f;
#pragma unroll
    for (int j = 0; j < 16; ++j) {
        int d = lane + j * 64;               // lane-consecutive: coalesced + bank-conflict-free
        float xv = xr[d];
        xw[d] = (bf16)xv;                    // fused convx: 128B/wave coalesced store
#pragma unroll
        for (int e = 0; e < NEXP; ++e) acc[e] += xv * gws[e][d];
    }
#pragma unroll
    for (int off = 32; off > 0; off >>= 1) {
#pragma unroll
        for (int e = 0; e < NEXP; ++e) acc[e] += __shfl_xor(acc[e], off, 64);
    }
    if (lane == 0) {
        float lg[NEXP], m = -1e30f;
        for (int e = 0; e < NEXP; ++e) { lg[e] = acc[e] + gb[e]; m = fmaxf(m, lg[e]); }
        float p[NEXP], s = 0.f;
        for (int e = 0; e < NEXP; ++e) { p[e] = expf(lg[e] - m); s += p[e]; }
        int e0 = 0;
        for (int e = 1; e < NEXP; ++e) if (p[e] > p[e0]) e0 = e;  // strict > : first index wins ties
        int e1 = (e0 == 0) ? 1 : 0;
        for (int e = 0; e < NEXP; ++e) if (e != e0 && p[e] > p[e1]) e1 = e;
        float g0 = p[e0] / s, g1 = p[e1] / s;
        float gs = g0 + g1 + 1e-9f;
        g0 /= gs; g1 /= gs;
        tok_e[wv * 2] = e0; tok_e[wv * 2 + 1] = e1;
        tok_g[wv * 2] = g0; tok_g[wv * 2 + 1] = g1;
        atomicAdd(&counts[e0], 1);
        atomicAdd(&counts[e1], 1);
    }
}

__global__ void scan_k(const int* __restrict__ counts, int* __restrict__ base)
{
    if (threadIdx.x == 0) {
        int s = 0;
#pragma unroll
        for (int e = 0; e < NEXP; ++e) { base[e] = s; s += counts[e]; }
        base[NEXP] = s;
    }
}

__global__ __launch_bounds__(256) void scatter_k(
    const int* __restrict__ tok_e, const float* __restrict__ tok_g,
    const int* __restrict__ base, int* __restrict__ counts2,
    int* __restrict__ row_token, float* __restrict__ row_gate, int* __restrict__ tok_row)
{
    int tk = blockIdx.x * 256 + threadIdx.x;
    if (tk >= NTOK) return;
#pragma unroll
    for (int k = 0; k < 2; ++k) {
        int e = tok_e[tk * 2 + k];
        int slot = atomicAdd(&counts2[e], 1);
        int r = base[e] + slot;
        row_token[r] = tk;
        row_gate[r] = tok_g[tk * 2 + k];
        tok_row[tk * 2 + k] = r;
    }
}

// ---- batched tile transpose + fp32->bf16 conversion:
// logical src M[r][c] (r<R, row stride sld, element offset soff) -> dst bf16 [c][r] (ld=R)
// per-expert strides es (src), ed (dst). grid: (C/64, R/64, NEXP)
// XOR-swizzled tile: phase-2 gathers along r and writes 128B-contiguous segments.
__global__ __launch_bounds__(256) void transpose_k(
    const float* __restrict__ src, bf16* __restrict__ dst,
    int R, int sld, size_t soff, size_t es, size_t ed)
{
    int e = blockIdx.z;
    bf16* d = dst + (size_t)e * ed;
    __shared__ __align__(16) bf16 tile[64 * 64];
    int t = threadIdx.x;
    int r0 = blockIdx.y * 64, c0 = blockIdx.x * 64;
#pragma unroll
    for (int i = 0; i < 2; ++i) {
        int c = t + i * 256;
        int rr = c >> 3, cc = c & 7;
        size_t eo = soff + (size_t)e * es + (size_t)(r0 + rr) * sld + c0 + cc * 8;
        floatx4 a = *(const floatx4*)(src + eo);
        floatx4 b = *(const floatx4*)(src + eo + 4);
        bf16x8 v;
#pragma unroll
        for (int j = 0; j < 4; ++j) { v[j] = (bf16)a[j]; v[4 + j] = (bf16)b[j]; }
        // store chunk cc of row rr at swizzled position p = cc ^ ((rr>>3)&7)
        *(bf16x8*)&tile[rr * 64 + ((cc ^ ((rr >> 3) & 7)) * 8)] = v;
    }
    __syncthreads();
#pragma unroll
    for (int i = 0; i < 2; ++i) {
        int c = t + i * 256;
        int oc = c >> 3;       // output row (a source column), 0..63
        int occ = c & 7;       // 16B chunk along r; 8 lanes -> 128B contiguous
        bf16x8 v;
#pragma unroll
        for (int j = 0; j < 8; ++j) {
            int r = occ * 8 + j;
            int p = (oc >> 3) ^ ((r >> 3) & 7);
            v[j] = tile[r * 64 + p * 8 + (oc & 7)];
        }
        *(bf16x8*)&d[(size_t)(c0 + oc) * R + r0 + occ * 8] = v;
    }
}

// ---------------- GEMM1: h[:, chunk] = gelu(gather(xb) @ w1[e][:, chunk] + b1[e][chunk]) ------
// w1t: per-expert [Nc][DIM] bf16 (k=DIM contiguous). hbuf: [NROW][Nc] bf16. b1 fp32.
// 2-buffer pipeline (32 KB LDS -> 5 blocks/CU) + fast branchless GELU epilogue.
__global__ __launch_bounds__(256) void gemm1_k(
    const bf16* __restrict__ xb, const bf16* __restrict__ w1t, const float* __restrict__ b1,
    const int* __restrict__ counts, const int* __restrict__ base,
    const int* __restrict__ row_token, bf16* __restrict__ hbuf, int Nc, int bias_off)
{
    const int e = blockIdx.z;
    const int cnt = counts[e];
    const int rt = blockIdx.y;
    if (rt * 128 >= cnt) return;
    const int rb = base[e] + rt * 128;
    const int rend = base[e] + cnt;
    const int n0 = blockIdx.x * 128;

    __shared__ __align__(16) bf16 As[2][128 * 32];   // 2 x 8 KB
    __shared__ __align__(16) bf16 Bs[2][128 * 32];   // 2 x 8 KB

    const int t = threadIdx.x;
    const int wv = t >> 6, lane = t & 63;
    // staging slots: slot s covers LDS 16B-chunk s = (row s>>2, pos s&3);
    // pos (s&3) holds data-chunk c = (s&3) ^ ((s>>3)&3)  [= (s&3) ^ ((row>>1)&3)]
    const int s0 = t, s1 = t + 256;
    const int ar0 = s0 >> 2, ac0 = (s0 & 3) ^ ((s0 >> 3) & 3);
    const int ar1 = s1 >> 2, ac1 = (s1 & 3) ^ ((s1 >> 3) & 3);
    int rr0 = rb + ar0; if (rr0 > NROW - 1) rr0 = NROW - 1;   // clamp: padded rows read valid data
    int rr1 = rb + ar1; if (rr1 > NROW - 1) rr1 = NROW - 1;
    const bf16* ga0 = xb + (size_t)row_token[rr0] * DIM + ac0 * 8;
    const bf16* ga1 = xb + (size_t)row_token[rr1] * DIM + ac1 * 8;
    const bf16* wb = w1t + (size_t)e * Nc * DIM;
    const bf16* gb0 = wb + (size_t)(n0 + ar0) * DIM + ac0 * 8;
    const bf16* gb1 = wb + (size_t)(n0 + ar1) * DIM + ac1 * 8;
    const int off0 = wv * 512, off1 = 2048 + wv * 512;   // wave-uniform LDS bases

    floatx4 acc[4][4];
#pragma unroll
    for (int i = 0; i < 4; ++i)
#pragma unroll
        for (int j = 0; j < 4; ++j) acc[i][j] = floatx4{0.f, 0.f, 0.f, 0.f};

    const int wr = (wv >> 1) * 64, wc = (wv & 1) * 64;
    const int lr = lane & 15;
    const int ck = lane >> 4;   // k-chunk 0..3

    // prologue: stage step 0 into buffer 0
    gl_lds16(ga0, &As[0][off0]); gl_lds16(ga1, &As[0][off1]);
    gl_lds16(gb0, &Bs[0][off0]); gl_lds16(gb1, &Bs[0][off1]);

    const int NSTEP = DIM / 32;   // 32
#pragma unroll 2
    for (int i = 0; i < NSTEP; ++i) {
        const int bc = i & 1;
        asm volatile("s_waitcnt vmcnt(0)" ::: "memory");   // own stage(i) landed (issued 1 step ago)
        __builtin_amdgcn_s_barrier();                      // all waves: stage(i) visible; buf^1 free
        asm volatile("" ::: "memory");
        if (i + 1 < NSTEP) {                               // stage(i+1) into the other buffer
            const int kn = (i + 1) * 32;
            gl_lds16(ga0 + kn, &As[bc ^ 1][off0]); gl_lds16(ga1 + kn, &As[bc ^ 1][off1]);
            gl_lds16(gb0 + kn, &Bs[bc ^ 1][off0]); gl_lds16(gb1 + kn, &Bs[bc ^ 1][off1]);
        }
        bf16x8 af[4], bg[4];
#pragma unroll
        for (int q = 0; q < 4; ++q) {
            int r = wr + q * 16 + lr;
            af[q] = *(const bf16x8*)&As[bc][r * 32 + ((ck ^ ((r >> 1) & 3)) * 8)];
        }
#pragma unroll
        for (int q = 0; q < 4; ++q) {
            int r = wc + q * 16 + lr;
            bg[q] = *(const bf16x8*)&Bs[bc][r * 32 + ((ck ^ ((r >> 1) & 3)) * 8)];
        }
        __builtin_amdgcn_s_setprio(1);
#pragma unroll
        for (int mi = 0; mi < 4; ++mi)
#pragma unroll
            for (int ni = 0; ni < 4; ++ni)
                acc[mi][ni] = __builtin_amdgcn_mfma_f32_16x16x32_bf16(af[mi], bg[ni], acc[mi][ni], 0, 0, 0);
        __builtin_amdgcn_s_setprio(0);
    }

#pragma unroll
    for (int mi = 0; mi < 4; ++mi) {
#pragma unroll
        for (int r = 0; r < 4; ++r) {
            int m = wr + mi * 16 + (lane >> 4) * 4 + r;  // C/D: row=(lane>>4)*4+reg, col=lane&15
            int gr = rb + m;
            if (gr < rend) {
#pragma unroll
                for (int ni = 0; ni < 4; ++ni) {
                    int col = n0 + wc + ni * 16 + lr;
                    float v = acc[mi][ni][r] + b1[e * HID + bias_off + col];
                    hbuf[(size_t)gr * Nc + col] = (bf16)gelu_f(v);
                }
            }
        }
    }
}

// ---------------- GEMM2 (split-K=2, non-atomic): y_ks += h[:, kslice] @ w2[e][kslice, :] -----
// w2t: per-expert [DIM][Kc] bf16 (k=Kc contiguous). hbuf: [NROW][Kc] bf16.
// ybuf: [KSPLIT][NROW][DIM] fp32. grid: (DIM/128, 32, NEXP*KSPLIT).
// v6: 3-buffer depth-2 counted-vmcnt pipeline (T3/T4) -- loads get ~2 full steps to land.
//     48 KB LDS -> 3 blocks/CU; with split-K's 1024 active blocks the grid can fill that.
__global__ __launch_bounds__(256) void gemm2_k(
    const bf16* __restrict__ hbuf, const bf16* __restrict__ w2t,
    const int* __restrict__ counts, const int* __restrict__ base,
    float* __restrict__ ybuf, int Kc, int first)
{
    const int e  = blockIdx.z >> 1;          // KSPLIT == 2
    const int ks = blockIdx.z & 1;
    const int cnt = counts[e];
    const int rt = blockIdx.y;
    if (rt * 128 >= cnt) return;
    const int rb = base[e] + rt * 128;
    const int rend = base[e] + cnt;
    const int n0 = blockIdx.x * 128;
    const int klen = Kc / KSPLIT;            // multiple of 64
    const int kbeg = ks * klen;

    __shared__ __align__(16) bf16 As[3][128 * 32];   // 3 x 8 KB
    __shared__ __align__(16) bf16 Bs[3][128 * 32];   // 3 x 8 KB

    const int t = threadIdx.x;
    const int wv = t >> 6, lane = t & 63;
    const int s0 = t, s1 = t + 256;
    const int ar0 = s0 >> 2, ac0 = (s0 & 3) ^ ((s0 >> 3) & 3);
    const int ar1 = s1 >> 2, ac1 = (s1 & 3) ^ ((s1 >> 3) & 3);
    int rr0 = rb + ar0; if (rr0 > NROW - 1) rr0 = NROW - 1;
    int rr1 = rb + ar1; if (rr1 > NROW - 1) rr1 = NROW - 1;
    const bf16* ga0 = hbuf + (size_t)rr0 * Kc + kbeg + ac0 * 8;
    const bf16* ga1 = hbuf + (size_t)rr1 * Kc + kbeg + ac1 * 8;
    const bf16* wb = w2t + (size_t)e * DIM * Kc;
    const bf16* gb0 = wb + (size_t)(n0 + ar0) * Kc + kbeg + ac0 * 8;
    const bf16* gb1 = wb + (size_t)(n0 + ar1) * Kc + kbeg + ac1 * 8;
    const int off0 = wv * 512, off1 = 2048 + wv * 512;

    floatx4 acc[4][4];
#pragma unroll
    for (int i = 0; i < 4; ++i)
#pragma unroll
        for (int j = 0; j < 4; ++j) acc[i][j] = floatx4{0.f, 0.f, 0.f, 0.f};

    const int wr = (wv >> 1) * 64, wc = (wv & 1) * 64;
    const int lr = lane & 15;
    const int ck = lane >> 4;

    // prologue: stage steps 0,1 into buffers 0,1
    gl_lds16(ga0,      &As[0][off0]); gl_lds16(ga1,      &As[0][off1]);
    gl_lds16(gb0,      &Bs[0][off0]); gl_lds16(gb1,      &Bs[0][off1]);
    gl_lds16(ga0 + 32, &As[1][off0]); gl_lds16(ga1 + 32, &As[1][off1]);
    gl_lds16(gb0 + 32, &Bs[1][off0]); gl_lds16(gb1 + 32, &Bs[1][off1]);

    const int nstep = klen >> 5;             // 64
    int bc = 0;                              // current buffer (i % 3)
    for (int i = 0; i < nstep; ++i) {
        // counted wait: newest 4 loads (stage i+1) stay in flight; stage(i) retired.
        if (i + 1 < nstep) asm volatile("s_waitcnt vmcnt(4)" ::: "memory");
        else               asm volatile("s_waitcnt vmcnt(0)" ::: "memory");
        __builtin_amdgcn_s_barrier();        // all waves: stage(i) visible in LDS
        asm volatile("" ::: "memory");
        if (i + 2 < nstep) {                 // issue stage(i+2) into buf (i+2)%3 (read-done in step i-1)
            int bs = bc + 2; if (bs >= 3) bs -= 3;
            const int kn = (i + 2) * 32;
            gl_lds16(ga0 + kn, &As[bs][off0]); gl_lds16(ga1 + kn, &As[bs][off1]);
            gl_lds16(gb0 + kn, &Bs[bs][off0]); gl_lds16(gb1 + kn, &Bs[bs][off1]);
        }
        bf16x8 af[4], bg[4];
#pragma unroll
        for (int q = 0; q < 4; ++q) {
            int r = wr + q * 16 + lr;
            af[q] = *(const bf16x8*)&As[bc][r * 32 + ((ck ^ ((r >> 1) & 3)) * 8)];
        }
#pragma unroll
        for (int q = 0; q < 4; ++q) {
            int r = wc + q * 16 + lr;
            bg[q] = *(const bf16x8*)&Bs[bc][r * 32 + ((ck ^ ((r >> 1) & 3)) * 8)];
        }
        __builtin_amdgcn_s_setprio(1);
#pragma unroll
        for (int mi = 0; mi < 4; ++mi)
#pragma unroll
            for (int ni = 0; ni < 4; ++ni)
                acc[mi][ni] = __builtin_amdgcn_mfma_f32_16x16x32_bf16(af[mi], bg[ni], acc[mi][ni], 0, 0, 0);
        __builtin_amdgcn_s_setprio(0);
        bc += 1; if (bc >= 3) bc -= 3;
    }

    float* yb = ybuf + (size_t)ks * NROW * DIM;
#pragma unroll
    for (int mi = 0; mi < 4; ++mi) {
#pragma unroll
        for (int r = 0; r < 4; ++r) {
            int m = wr + mi * 16 + (lane >> 4) * 4 + r;
            int gr = rb + m;
            if (gr < rend) {
#pragma unroll
                for (int ni = 0; ni < 4; ++ni) {
                    int col = n0 + wc + ni * 16 + lr;
                    size_t idx = (size_t)gr * DIM + col;
                    float v = acc[mi][ni][r];
                    yb[idx] = first ? v : (yb[idx] + v);
                }
            }
        }
    }
}

// ---------------- combine: out[t] = Σ_k g_k * (y0[row_k] + y1[row_k] + b2[e_k]) --------------
__global__ __launch_bounds__(256) void combine_k(
    const float* __restrict__ ybuf, const int* __restrict__ tok_row,
    const int* __restrict__ tok_e, const float* __restrict__ tok_g,
    const float* __restrict__ b2, float* __restrict__ out)
{
    int i = blockIdx.x * 256 + threadIdx.x;
    int tk = i >> 8;            // DIM/4 == 256 chunks per token
    int dc = (i & 255) * 4;
    int ra = tok_row[tk * 2], rbx = tok_row[tk * 2 + 1];
    int ea = tok_e[tk * 2],  eb = tok_e[tk * 2 + 1];
    float ga = tok_g[tk * 2], gbv = tok_g[tk * 2 + 1];
    const float* y0 = ybuf;
    const float* y1 = ybuf + (size_t)NROW * DIM;
    floatx4 a0 = *(const floatx4*)&y0[(size_t)ra * DIM + dc];
    floatx4 a1 = *(const floatx4*)&y1[(size_t)ra * DIM + dc];
    floatx4 b0 = *(const floatx4*)&y0[(size_t)rbx * DIM + dc];
    floatx4 b1v = *(const floatx4*)&y1[(size_t)rbx * DIM + dc];
    floatx4 b2a = *(const floatx4*)&b2[ea * DIM + dc];
    floatx4 b2b = *(const floatx4*)&b2[eb * DIM + dc];
    floatx4 o;
#pragma unroll
    for (int j = 0; j < 4; ++j)
        o[j] = ga * (a0[j] + a1[j] + b2a[j]) + gbv * (b0[j] + b1v[j] + b2b[j]);
    *(floatx4*)&out[(size_t)tk * DIM + dc] = o;
}

extern "C" void kernel_launch(void* const* d_in, const int* in_sizes, int n_in,
                              void* d_out, int out_size, void* d_ws, size_t ws_size,
                              hipStream_t stream)
{
    const float* x  = (const float*)d_in[0];
    const float* gw = (const float*)d_in[1];
    const float* gb = (const float*)d_in[2];
    const float* w1 = (const float*)d_in[3];
    const float* b1 = (const float*)d_in[4];
    const float* w2 = (const float*)d_in[5];
    const float* b2 = (const float*)d_in[6];
    float* out = (float*)d_out;

    char* w = (char*)d_ws;
    int*   counts  = (int*)(w + 0);        // 8 ints
    int*   counts2 = (int*)(w + 32);       // 8 ints
    int*   base    = (int*)(w + 64);       // 9 ints
    int*   tok_e   = (int*)(w + 256);
    float* tok_g   = (float*)(w + 256 + 32768);
    int*   row_tok = (int*)(w + 256 + 2 * 32768);
    float* row_g   = (float*)(w + 256 + 3 * 32768);
    int*   tok_row = (int*)(w + 256 + 4 * 32768);
    size_t off = 256 + 5 * 32768;                                       // 256-aligned
    bf16*  xb   = (bf16*)(w + off);   off += (size_t)NTOK * DIM * 2;    // 8 MiB
    float* ybuf = (float*)(w + off);  off += (size_t)KSPLIT * NROW * DIM * 4;  // 64 MiB

    // choose H-chunk so total footprint fits ws_size (deterministic across calls)
    int Hc = HID;
    for (;;) {
        size_t need = off + (size_t)NEXP * Hc * DIM * 2 + (size_t)NROW * Hc * 2;
        if (need <= ws_size || Hc == 128) break;
        Hc >>= 1;
    }
    bf16* wT   = (bf16*)(w + off);  off += (size_t)NEXP * Hc * DIM * 2;  // per chunk: w1^T slice, then w2^T slice
    bf16* hbuf = (bf16*)(w + off);                                       // [NROW][Hc]

    zero_k<<<1, 64, 0, stream>>>(counts);
    router_k<<<NTOK / 4, 256, 0, stream>>>(x, gw, gb, counts, tok_e, tok_g, xb);
    scan_k<<<1, 64, 0, stream>>>(counts, base);
    scatter_k<<<NTOK / 256, 256, 0, stream>>>(tok_e, tok_g, base, counts2, row_tok, row_g, tok_row);

    const int nc = HID / Hc;
    for (int ch = 0; ch < nc; ++ch) {
        // w1[e] cols [ch*Hc, +Hc): logical [DIM][Hc] row-stride HID -> wT [Hc][DIM]
        transpose_k<<<dim3(Hc / 64, DIM / 64, NEXP), 256, 0, stream>>>(
            w1, wT, DIM, HID, (size_t)ch * Hc, (size_t)DIM * HID, (size_t)Hc * DIM);
        gemm1_k<<<dim3(Hc / 128, 32, NEXP), 256, 0, stream>>>(
            xb, wT, b1, counts, base, row_tok, hbuf, Hc, ch * Hc);
        // w2[e] rows [ch*Hc, +Hc): logical [Hc][DIM] contiguous -> wT [DIM][Hc]
        transpose_k<<<dim3(DIM / 64, Hc / 64, NEXP), 256, 0, stream>>>(
            w2, wT, Hc, DIM, (size_t)ch * Hc * DIM, (size_t)HID * DIM, (size_t)DIM * Hc);
        gemm2_k<<<dim3(DIM / 128, 32, NEXP * KSPLIT), 256, 0, stream>>>(
            hbuf, wT, counts, base, ybuf, Hc, ch == 0);
    }

    combine_k<<<NTOK, 256, 0, stream>>>(ybuf, tok_row, tok_e, tok_g, b2, out);
}